// Round 11
// baseline (554.137 us; speedup 1.0000x reference)
//
#include <hip/hip_runtime.h>
#include <math.h>

#define N_PIX (512*512)
#define S_SEG 1024
#define CDIM  256
#define BATCH 8

typedef __attribute__((ext_vector_type(4))) float f32x4;
typedef __attribute__((ext_vector_type(8))) short bf16x8;
typedef __fp16 half2v __attribute__((ext_vector_type(2)));
typedef __attribute__((address_space(3))) unsigned int lds_uint;

__device__ __forceinline__ float lrelu(float v) { return v > 0.f ? v : 0.2f * v; }

__device__ __forceinline__ unsigned short bf16_hi(float x) {
    union { float f; unsigned int u; } v; v.f = x;
    unsigned int r = v.u + 0x7FFFu + ((v.u >> 16) & 1u);
    return (unsigned short)(r >> 16);
}
__device__ __forceinline__ float bf16_tof(unsigned short h) {
    union { float f; unsigned int u; } v; v.u = ((unsigned int)h) << 16;
    return v.f;
}
__device__ __forceinline__ float dot4(float4 a, float4 b) {
    return a.x * b.x + a.y * b.y + a.z * b.z + a.w * b.w;
}
__device__ __forceinline__ unsigned pack_h2(float lo, float hi) {
    union { half2v h; unsigned u; } c;
    c.h = __builtin_amdgcn_cvt_pkrtz(lo, hi);
    return c.u;
}
__device__ __forceinline__ void ds_pk_add(lds_uint* p, unsigned val) {
    asm volatile("ds_pk_add_f16 %0, %1"
                 :: "v"((unsigned)(unsigned long)p), "v"(val) : "memory");
}

// ---------------------------------------------------------------------------
// MERGED prep, ATOMIC-FREE flush: per-block bins -> global slabs (coalesced
// stores), reductions deferred to prep_xin. Removes the 1M global fp atomics
// that were the invariant 52us wall.
//   blocks [0,256)    : segment pooling -> seg_slab[blk][1024] float4
//   blocks [256,512)  : A -> bf16 hi/lo split; col partials -> A_slab
//   blocks [512,640)  : blk_w -> Wh/Wl split (scaled by sc_c)
//   block  640        : proj_w -> wpad
// ---------------------------------------------------------------------------
__global__ __launch_bounds__(1024) void prep_all_kernel(
    const float* __restrict__ images, const int* __restrict__ seg,
    float* __restrict__ seg_slab,
    const float* __restrict__ A, unsigned short* __restrict__ Ah,
    unsigned short* __restrict__ Al, float* __restrict__ A_slab,
    const float* __restrict__ blk_w, unsigned short* __restrict__ Wh,
    unsigned short* __restrict__ Wl, float sc_c,
    const float* __restrict__ proj_w, float* __restrict__ wpad)
{
    __shared__ unsigned int sm[2048];
    const int blk = blockIdx.x;
    const int t = threadIdx.x;

    if (blk < 256) {
        // ---- segment pooling into LDS fp16-packed bins ----
        const int b = blk >> 5;
        const int chunk = blk & 31;
        for (int i = t; i < S_SEG * 2; i += 1024) sm[i] = 0u;
        __syncthreads();

        lds_uint* bl2 = (lds_uint*)sm;
        const float4* imr = (const float4*)(images + (size_t)b * 3 * N_PIX);
        const float4* img = imr + N_PIX / 4;
        const float4* imb = img + N_PIX / 4;
        const int4* sg4 = (const int4*)(seg + (size_t)b * N_PIX);
        const int base4 = chunk * (N_PIX / 32 / 4);

#pragma unroll
        for (int it = 0; it < 2; ++it) {
            int p4 = base4 + it * 1024 + t;
            int4 s = sg4[p4];
            float4 r = imr[p4];
            float4 g = img[p4];
            float4 bb = imb[p4];
            ds_pk_add(bl2 + s.x * 2 + 0, pack_h2(r.x, g.x));
            ds_pk_add(bl2 + s.x * 2 + 1, pack_h2(bb.x, 1.f));
            ds_pk_add(bl2 + s.y * 2 + 0, pack_h2(r.y, g.y));
            ds_pk_add(bl2 + s.y * 2 + 1, pack_h2(bb.y, 1.f));
            ds_pk_add(bl2 + s.z * 2 + 0, pack_h2(r.z, g.z));
            ds_pk_add(bl2 + s.z * 2 + 1, pack_h2(bb.z, 1.f));
            ds_pk_add(bl2 + s.w * 2 + 0, pack_h2(r.w, g.w));
            ds_pk_add(bl2 + s.w * 2 + 1, pack_h2(bb.w, 1.f));
        }
        __syncthreads();
        if (t < S_SEG) {
            union { unsigned u; __fp16 h[2]; } p0, p1;
            p0.u = sm[t * 2 + 0];
            p1.u = sm[t * 2 + 1];
            float4 o;
            o.x = (float)p0.h[0];
            o.y = (float)p0.h[1];
            o.z = (float)p1.h[0];
            o.w = (float)p1.h[1];
            ((float4*)seg_slab)[(size_t)blk * 1024 + t] = o;   // NO atomics
        }
        return;
    }

    if (blk < 512) {
        // ---- A split + per-chunk column partial sums ----
        const int ablk = blk - 256;
        if (t < 256) {
            const int b = ablk >> 5;
            const int chunk = ablk & 31;
            const size_t base4 = ((size_t)b * 1024 * 1024 + (size_t)chunk * 32 * 1024) >> 2;
            const float4* Af = ((const float4*)A) + base4;
            ushort4* Ahf = ((ushort4*)Ah) + base4;
            ushort4* Alf = ((ushort4*)Al) + base4;
            float a0 = 0.f, a1 = 0.f, a2 = 0.f, a3 = 0.f;
#pragma unroll 4
            for (int r = 0; r < 32; ++r) {
                float4 v = Af[r * 256 + t];
                ushort4 h, l;
                h.x = bf16_hi(v.x); l.x = bf16_hi(v.x - bf16_tof(h.x));
                h.y = bf16_hi(v.y); l.y = bf16_hi(v.y - bf16_tof(h.y));
                h.z = bf16_hi(v.z); l.z = bf16_hi(v.z - bf16_tof(h.z));
                h.w = bf16_hi(v.w); l.w = bf16_hi(v.w - bf16_tof(h.w));
                Ahf[r * 256 + t] = h;
                Alf[r * 256 + t] = l;
                a0 += v.x; a1 += v.y; a2 += v.z; a3 += v.w;
            }
            float4 o; o.x = a0; o.y = a1; o.z = a2; o.w = a3;
            ((float4*)A_slab)[(size_t)ablk * 256 + t] = o;     // NO atomics
        }
        return;
    }

    if (blk < 640) {
        unsigned int idx = (blk - 512) * 1024 + t;
        float4 v = ((const float4*)blk_w)[idx];
        ushort4 h, l;
        float a;
        a = v.x * sc_c; h.x = bf16_hi(a); l.x = bf16_hi(a - bf16_tof(h.x));
        a = v.y * sc_c; h.y = bf16_hi(a); l.y = bf16_hi(a - bf16_tof(h.y));
        a = v.z * sc_c; h.z = bf16_hi(a); l.z = bf16_hi(a - bf16_tof(h.z));
        a = v.w * sc_c; h.w = bf16_hi(a); l.w = bf16_hi(a - bf16_tof(h.w));
        ((ushort4*)Wh)[idx] = h;
        ((ushort4*)Wl)[idx] = l;
        return;
    }

    for (int i = t; i < 256 * 144; i += 1024) {
        int n = i / 144, k = i % 144;
        wpad[i] = (k < 131) ? proj_w[n * 131 + k] : 0.f;
    }
}

// ---------------------------------------------------------------------------
// prep_xin + slab reductions. grid 4640 blocks x 256:
//   blocks [0,4608)   : xin build; c<3 lanes reduce seg_slab (32 chunks)
//   blocks [4608,4640): abar = colmean reduction of A_slab + sumabar
// ---------------------------------------------------------------------------
__global__ __launch_bounds__(256) void prep_xin_kernel(
    const float* __restrict__ seg_slab, const float* __restrict__ A_slab,
    const float* __restrict__ z, float* __restrict__ xin,
    float* __restrict__ abar, float* __restrict__ sumabar)
{
    const int t = threadIdx.x;
    if (blockIdx.x >= 4608) {
        int idx = (blockIdx.x - 4608) * 256 + t;   // 0..8191
        int b = idx >> 10, s = idx & 1023;
        float acc = 0.f;
        const float* sl = A_slab + (size_t)(b << 5) * 1024 + s;
#pragma unroll 8
        for (int ch = 0; ch < 32; ++ch) acc += sl[ch * 1024];
        float v = acc * (1.f / 1024.f);
        abar[idx] = v;
        __shared__ float red[256];
        red[t] = v;
        __syncthreads();
        for (int off = 128; off > 0; off >>= 1) {
            if (t < off) red[t] += red[t + off];
            __syncthreads();
        }
        if (t == 0) atomicAdd(&sumabar[b], red[0]);   // 32 atomics total
        return;
    }

    int idx = blockIdx.x * 256 + t;
    int r = idx / 144, c = idx % 144;
    int b = r >> 10;
    float v;
    if (c < 3) {
        int s = r & 1023;
        const float4* sl = (const float4*)seg_slab + (size_t)(b << 5) * 1024 + s;
        float cnt = 0.f, sc = 0.f;
#pragma unroll 8
        for (int ch = 0; ch < 32; ++ch) {
            float4 w = sl[ch * 1024];
            cnt += w.w;
            sc += (c == 0) ? w.x : ((c == 1) ? w.y : w.z);
        }
        v = sc / (cnt + 1e-6f);
    } else if (c < 131) {
        v = z[b * 128 + (c - 3)];
    } else {
        v = 0.f;
    }
    xin[idx] = v;
}

// ---------------------------------------------------------------------------
// staging helpers (rule #21 both-sides swizzle); T = block thread count
// ---------------------------------------------------------------------------
__device__ __forceinline__ void stage_tile(
    const unsigned short* __restrict__ g, int grow,
    unsigned short* lds, int tid, int nissue, int T)
{
    for (int i = 0; i < nissue; ++i) {
        int c = i * T + tid;
        int row = c >> 3, cin = c & 7;
        int cs = cin ^ (row & 7);
        const unsigned short* src = g + (size_t)row * grow + cs * 8;
        unsigned short* dst = lds + (size_t)(i * T + (tid & ~63)) * 8;
        __builtin_amdgcn_global_load_lds(
            (const __attribute__((address_space(1))) unsigned int*)src,
            (__attribute__((address_space(3))) unsigned int*)dst, 16, 0, 0);
    }
}

__device__ __forceinline__ int frag_idx(int row, int ks, int l)
{
    int chunk = (ks * 4 + (l >> 4)) ^ (row & 7);
    return row * 64 + chunk * 8;
}

// ---------------------------------------------------------------------------
// MFMA split-3 GEMM: x_out = lrelu(gamma*(A @ h1) + beta) + optional outputs.
// Tile 64x128 (grid 16x2x8), 512 threads / 8 waves, wave-tile 32x32.
// ---------------------------------------------------------------------------
__global__ __launch_bounds__(512) void gemm_nn_mfma_kernel(
    const unsigned short* __restrict__ Ah_g, const unsigned short* __restrict__ Al_g,
    const unsigned short* __restrict__ Hh_g, const unsigned short* __restrict__ Hl_g,
    const float* __restrict__ style, const float* __restrict__ abar,
    float* __restrict__ x, unsigned short* __restrict__ xh,
    unsigned short* __restrict__ xl, float* __restrict__ mv)
{
    __shared__ __align__(16) unsigned short Ah_s[64 * 64];
    __shared__ __align__(16) unsigned short Al_s[64 * 64];
    __shared__ __align__(16) unsigned short Bh_s[128 * 64];
    __shared__ __align__(16) unsigned short Bl_s[128 * 64];
    __shared__ float mvred[128];
    const int tid = threadIdx.x;
    const int b = blockIdx.z, bm = blockIdx.x, bn = blockIdx.y;
    const int l = tid & 63, wave = tid >> 6;
    const int wr = wave >> 2, wc = wave & 3;
    if (mv && tid < 128) mvred[tid] = 0.f;

    const unsigned short* Ag_h = Ah_g + ((size_t)(b * 1024 + bm * 64)) * 1024;
    const unsigned short* Ag_l = Al_g + ((size_t)(b * 1024 + bm * 64)) * 1024;
    const unsigned short* Hg_h = Hh_g + ((size_t)(b * 256 + bn * 128)) * 1024;
    const unsigned short* Hg_l = Hl_g + ((size_t)(b * 256 + bn * 128)) * 1024;

    f32x4 acc[2][2];
#pragma unroll
    for (int i = 0; i < 2; ++i)
#pragma unroll
        for (int j = 0; j < 2; ++j) acc[i][j] = (f32x4){0.f, 0.f, 0.f, 0.f};

    for (int kt = 0; kt < 16; ++kt) {
        stage_tile(Ag_h + kt * 64, 1024, Ah_s, tid, 1, 512);
        stage_tile(Ag_l + kt * 64, 1024, Al_s, tid, 1, 512);
        stage_tile(Hg_h + kt * 64, 1024, Bh_s, tid, 2, 512);
        stage_tile(Hg_l + kt * 64, 1024, Bl_s, tid, 2, 512);
        __syncthreads();
#pragma unroll
        for (int ks = 0; ks < 2; ++ks) {
            bf16x8 ah[2], al[2], bh[2], bl[2];
#pragma unroll
            for (int fm = 0; fm < 2; ++fm) {
                int row = wr * 32 + fm * 16 + (l & 15);
                int idx = frag_idx(row, ks, l);
                ah[fm] = *(const bf16x8*)&Ah_s[idx];
                al[fm] = *(const bf16x8*)&Al_s[idx];
            }
#pragma unroll
            for (int fn = 0; fn < 2; ++fn) {
                int row = wc * 32 + fn * 16 + (l & 15);
                int idx = frag_idx(row, ks, l);
                bh[fn] = *(const bf16x8*)&Bh_s[idx];
                bl[fn] = *(const bf16x8*)&Bl_s[idx];
            }
#pragma unroll
            for (int fm = 0; fm < 2; ++fm)
#pragma unroll
                for (int fn = 0; fn < 2; ++fn) {
                    acc[fm][fn] = __builtin_amdgcn_mfma_f32_16x16x32_bf16(ah[fm], bh[fn], acc[fm][fn], 0, 0, 0);
                    acc[fm][fn] = __builtin_amdgcn_mfma_f32_16x16x32_bf16(ah[fm], bl[fn], acc[fm][fn], 0, 0, 0);
                    acc[fm][fn] = __builtin_amdgcn_mfma_f32_16x16x32_bf16(al[fm], bh[fn], acc[fm][fn], 0, 0, 0);
                }
        }
        __syncthreads();
    }

    const float* st = style + b * 2 * CDIM;
#pragma unroll
    for (int fn = 0; fn < 2; ++fn) {
        int col = bn * 128 + wc * 32 + fn * 16 + (l & 15);
        float ga = st[col], be = st[CDIM + col];
        float pmv = 0.f;
#pragma unroll
        for (int fm = 0; fm < 2; ++fm) {
            int m0 = bm * 64 + wr * 32 + fm * 16 + (l >> 4) * 4;
#pragma unroll
            for (int r = 0; r < 4; ++r) {
                float v = lrelu(ga * acc[fm][fn][r] + be);
                size_t off = ((size_t)(b * 1024 + m0 + r)) * 256 + col;
                if (x) x[off] = v;
                if (xh) {
                    unsigned short h = bf16_hi(v);
                    xh[off] = h;
                    xl[off] = bf16_hi(v - bf16_tof(h));
                }
                pmv += abar[b * 1024 + m0 + r] * v;
            }
        }
        if (mv) atomicAdd(&mvred[wc * 32 + fn * 16 + (l & 15)], pmv);
    }
    if (mv) {
        __syncthreads();
        if (tid < 128) atomicAdd(&mv[b * 256 + bn * 128 + tid], mvred[tid]);
    }
}

// ---------------------------------------------------------------------------
// MFMA split-3 GEMM (h1 = x @ W'^T + b, transposed bf16 output), 512 thr /
// 8 waves, PLUS the per-batch style MLP at blockIdx.y == 4 (wave-per-output).
// ---------------------------------------------------------------------------
__global__ __launch_bounds__(512) void gemm_nt_mfma_kernel(
    const unsigned short* __restrict__ xh_g, const unsigned short* __restrict__ xl_g,
    const unsigned short* __restrict__ Wh, const unsigned short* __restrict__ Wl,
    const float* __restrict__ bias,
    unsigned short* __restrict__ h1t_h, unsigned short* __restrict__ h1t_l,
    const float* __restrict__ mv, const float* __restrict__ sumabar,
    const float* __restrict__ Wblk_f,
    const float* __restrict__ W1, const float* __restrict__ b1,
    const float* __restrict__ W2, const float* __restrict__ b2,
    float* __restrict__ style, float sc_c, float sc_2c)
{
    __shared__ __align__(16) unsigned short Ah_s[128 * 64];
    __shared__ __align__(16) unsigned short Al_s[128 * 64];
    __shared__ __align__(16) unsigned short Bh_s[64 * 64];
    __shared__ __align__(16) unsigned short Bl_s[64 * 64];
    const int tid = threadIdx.x;
    const int bm = blockIdx.x, bn = blockIdx.y;

    if (bn == 4) {
        if (bm >= BATCH * 4) return;
        const int bb = bm >> 2;
        const int q = bm & 3;
        const int w = tid >> 6, lane = tid & 63;
        float* m_s = (float*)Ah_s;
        float* s1_s = (float*)Bh_s;

        const float4 mvreg = *(const float4*)&mv[bb * 256 + lane * 4];
        const float sab = sumabar[bb];

        for (int g = 0; g < 4; ++g) {
            const int o0 = w * 32 + g * 8;
            float p[8];
#pragma unroll
            for (int j = 0; j < 8; ++j) {
                const float4 wv = *(const float4*)&Wblk_f[(size_t)(o0 + j) * 256 + lane * 4];
                p[j] = dot4(wv, mvreg);
            }
#pragma unroll
            for (int off = 32; off > 0; off >>= 1)
#pragma unroll
                for (int j = 0; j < 8; ++j) p[j] += __shfl_xor(p[j], off);
            if (lane == 0)
#pragma unroll
                for (int j = 0; j < 8; ++j)
                    m_s[o0 + j] = sc_c * p[j] + sab * bias[o0 + j];
        }
        __syncthreads();
        const float4 mreg = *(const float4*)&m_s[lane * 4];

        for (int g = 0; g < 8; ++g) {
            const int o0 = w * 64 + g * 8;
            float p[8];
#pragma unroll
            for (int j = 0; j < 8; ++j) {
                const float4 wv = *(const float4*)&W1[(size_t)(o0 + j) * 256 + lane * 4];
                p[j] = dot4(wv, mreg);
            }
#pragma unroll
            for (int off = 32; off > 0; off >>= 1)
#pragma unroll
                for (int j = 0; j < 8; ++j) p[j] += __shfl_xor(p[j], off);
            if (lane == 0)
#pragma unroll
                for (int j = 0; j < 8; ++j)
                    s1_s[o0 + j] = lrelu(sc_c * p[j] + b1[o0 + j]);
        }
        __syncthreads();
        const float4 sa = *(const float4*)&s1_s[lane * 4];
        const float4 sb = *(const float4*)&s1_s[256 + lane * 4];

        for (int g = 0; g < 2; ++g) {
            const int o0 = q * 128 + w * 16 + g * 8;
            float p[8];
#pragma unroll
            for (int j = 0; j < 8; ++j) {
                const float4 wa = *(const float4*)&W2[(size_t)(o0 + j) * 512 + lane * 4];
                const float4 wb = *(const float4*)&W2[(size_t)(o0 + j) * 512 + 256 + lane * 4];
                p[j] = dot4(wa, sa) + dot4(wb, sb);
            }
#pragma unroll
            for (int off = 32; off > 0; off >>= 1)
#pragma unroll
                for (int j = 0; j < 8; ++j) p[j] += __shfl_xor(p[j], off);
            if (lane == 0)
#pragma unroll
                for (int j = 0; j < 8; ++j)
                    style[bb * 512 + o0 + j] = sc_2c * p[j] + b2[o0 + j];
        }
        return;
    }

    // ---- GEMM path (8 waves, wave-tile 64x16) ----
    const int l = tid & 63, wave = tid >> 6;
    const int wr = wave >> 2, wc = wave & 3;
    const int row0 = bm * 128;
    const int b = row0 >> 10;

    const unsigned short* Ag_h = xh_g + (size_t)row0 * 256;
    const unsigned short* Ag_l = xl_g + (size_t)row0 * 256;
    const unsigned short* Bg_h = Wh + (size_t)(bn * 64) * 256;
    const unsigned short* Bg_l = Wl + (size_t)(bn * 64) * 256;

    f32x4 acc[4];
#pragma unroll
    for (int i = 0; i < 4; ++i) acc[i] = (f32x4){0.f, 0.f, 0.f, 0.f};

    for (int kt = 0; kt < 4; ++kt) {
        stage_tile(Ag_h + kt * 64, 256, Ah_s, tid, 2, 512);
        stage_tile(Ag_l + kt * 64, 256, Al_s, tid, 2, 512);
        stage_tile(Bg_h + kt * 64, 256, Bh_s, tid, 1, 512);
        stage_tile(Bg_l + kt * 64, 256, Bl_s, tid, 1, 512);
        __syncthreads();
#pragma unroll
        for (int ks = 0; ks < 2; ++ks) {
            bf16x8 ah[4], al[4], bh, bl;
#pragma unroll
            for (int fm = 0; fm < 4; ++fm) {
                int row = wr * 64 + fm * 16 + (l & 15);
                int idx = frag_idx(row, ks, l);
                ah[fm] = *(const bf16x8*)&Ah_s[idx];
                al[fm] = *(const bf16x8*)&Al_s[idx];
            }
            {
                int row = wc * 16 + (l & 15);
                int idx = frag_idx(row, ks, l);
                bh = *(const bf16x8*)&Bh_s[idx];
                bl = *(const bf16x8*)&Bl_s[idx];
            }
#pragma unroll
            for (int fm = 0; fm < 4; ++fm) {
                acc[fm] = __builtin_amdgcn_mfma_f32_16x16x32_bf16(ah[fm], bh, acc[fm], 0, 0, 0);
                acc[fm] = __builtin_amdgcn_mfma_f32_16x16x32_bf16(ah[fm], bl, acc[fm], 0, 0, 0);
                acc[fm] = __builtin_amdgcn_mfma_f32_16x16x32_bf16(al[fm], bh, acc[fm], 0, 0, 0);
            }
        }
        __syncthreads();
    }

    {
        int col = bn * 64 + wc * 16 + (l & 15);
        float bi = bias[col];
#pragma unroll
        for (int fm = 0; fm < 4; ++fm) {
            int s0 = (row0 & 1023) + wr * 64 + fm * 16 + (l >> 4) * 4;
            float v0 = acc[fm][0] + bi;
            float v1 = acc[fm][1] + bi;
            float v2 = acc[fm][2] + bi;
            float v3 = acc[fm][3] + bi;
            ushort4 hv, lv;
            hv.x = bf16_hi(v0); lv.x = bf16_hi(v0 - bf16_tof(hv.x));
            hv.y = bf16_hi(v1); lv.y = bf16_hi(v1 - bf16_tof(hv.y));
            hv.z = bf16_hi(v2); lv.z = bf16_hi(v2 - bf16_tof(hv.z));
            hv.w = bf16_hi(v3); lv.w = bf16_hi(v3 - bf16_tof(hv.w));
            size_t off = ((size_t)(b * 256 + col)) * 1024 + s0;
            *(ushort4*)&h1t_h[off] = hv;
            *(ushort4*)&h1t_l[off] = lv;
        }
    }
}

// ---------------------------------------------------------------------------
// fp32 VALU gemm_nt (proj only) + mv + bf16 emit
// ---------------------------------------------------------------------------
#define BM 64
#define BN 64
#define BK 16
__global__ __launch_bounds__(256) void gemm_nt_kernel(
    const float* __restrict__ A, const float* __restrict__ B,
    float* __restrict__ C, int K, float alpha, const float* __restrict__ bias,
    const float* __restrict__ abar, float* __restrict__ mv,
    unsigned short* __restrict__ xh, unsigned short* __restrict__ xl)
{
    __shared__ float As[BK][BM + 4];
    __shared__ float Bs[BK][BN + 4];
    __shared__ float red[16][BN];
    const int tid = threadIdx.x;
    const int bm = blockIdx.x, bn = blockIdx.y;
    const int tx = tid & 15, ty = tid >> 4;
    const int lrow = tid >> 2;
    const int lk = (tid & 3) << 2;
    const float* Ag = A + (size_t)(bm * BM + lrow) * K + lk;
    const float* Bg = B + (size_t)(bn * BN + lrow) * K + lk;
    float acc[4][4] = {};

    for (int k0 = 0; k0 < K; k0 += BK) {
        float4 av = *(const float4*)(Ag + k0);
        float4 bv = *(const float4*)(Bg + k0);
        __syncthreads();
        As[lk + 0][lrow] = av.x; As[lk + 1][lrow] = av.y;
        As[lk + 2][lrow] = av.z; As[lk + 3][lrow] = av.w;
        Bs[lk + 0][lrow] = bv.x; Bs[lk + 1][lrow] = bv.y;
        Bs[lk + 2][lrow] = bv.z; Bs[lk + 3][lrow] = bv.w;
        __syncthreads();
#pragma unroll
        for (int kk = 0; kk < BK; ++kk) {
            const float4 a = *(const float4*)&As[kk][ty << 2];
            const float4 b = *(const float4*)&Bs[kk][tx << 2];
            float ar[4] = {a.x, a.y, a.z, a.w};
            float br[4] = {b.x, b.y, b.z, b.w};
#pragma unroll
            for (int i = 0; i < 4; ++i)
#pragma unroll
                for (int j = 0; j < 4; ++j)
                    acc[i][j] += ar[i] * br[j];
        }
    }
    const int row = bm * BM + (ty << 2);
    const int col = bn * BN + (tx << 2);
    const int b = row >> 10;
    float bi[4] = {bias[col], bias[col + 1], bias[col + 2], bias[col + 3]};
    float o[4][4];
#pragma unroll
    for (int i = 0; i < 4; ++i) {
        float4 ov;
        ov.x = o[i][0] = alpha * acc[i][0] + bi[0];
        ov.y = o[i][1] = alpha * acc[i][1] + bi[1];
        ov.z = o[i][2] = alpha * acc[i][2] + bi[2];
        ov.w = o[i][3] = alpha * acc[i][3] + bi[3];
        *(float4*)(C + (size_t)(row + i) * CDIM + col) = ov;
#pragma unroll
        for (int j = 0; j < 4; ++j) {
            size_t off = (size_t)(row + i) * CDIM + col + j;
            unsigned short h = bf16_hi(o[i][j]);
            xh[off] = h;
            xl[off] = bf16_hi(o[i][j] - bf16_tof(h));
        }
    }
    {
        float p[4];
#pragma unroll
        for (int j = 0; j < 4; ++j) {
            p[j] = 0.f;
#pragma unroll
            for (int i = 0; i < 4; ++i)
                p[j] += abar[((row + i) & 1023) + (b << 10)] * o[i][j];
            red[ty][(tx << 2) + j] = p[j];
        }
        __syncthreads();
        if (tid < BN) {
            float s = 0.f;
#pragma unroll
            for (int t = 0; t < 16; ++t) s += red[t][tid];
            atomicAdd(&mv[b * CDIM + bn * BN + tid], s);
        }
    }
}

// ---------------------------------------------------------------------------
// color: writes tanh'd color table
// ---------------------------------------------------------------------------
__global__ __launch_bounds__(256) void color_kernel(
    const float* __restrict__ x, const float* __restrict__ rgb_w,
    const float* __restrict__ rgb_b, float* __restrict__ color, float sc_c)
{
    const int wave = threadIdx.x >> 6;
    const int lane = threadIdx.x & 63;
    const int r = blockIdx.x * 4 + wave;
    const float4 xv = *(const float4*)(x + (size_t)r * CDIM + lane * 4);
    float p[3];
#pragma unroll
    for (int cc = 0; cc < 3; ++cc) {
        const float4 wv = *(const float4*)(rgb_w + cc * CDIM + lane * 4);
        p[cc] = xv.x * wv.x + xv.y * wv.y + xv.z * wv.z + xv.w * wv.w;
    }
#pragma unroll
    for (int off = 32; off > 0; off >>= 1) {
#pragma unroll
        for (int cc = 0; cc < 3; ++cc) p[cc] += __shfl_down(p[cc], off);
    }
    if (lane == 0) {
#pragma unroll
        for (int cc = 0; cc < 3; ++cc)
            color[(size_t)r * 3 + cc] = tanhf(sc_c * p[cc] + rgb_b[cc]);
    }
}

// ---------------------------------------------------------------------------
// gather: 4 pixels/thread, float4 stores per plane; color already tanh'd
// ---------------------------------------------------------------------------
__global__ __launch_bounds__(256) void gather_kernel(
    const int* __restrict__ seg, const float* __restrict__ color,
    float* __restrict__ out)
{
    int idx = blockIdx.x * 256 + threadIdx.x;
    int b = idx >> 16;
    int p4 = idx & 65535;
    int4 s = ((const int4*)(seg + (size_t)b * N_PIX))[p4];
    const float* cb = color + (size_t)b * S_SEG * 3;
    float4 o0, o1, o2;
    o0.x = cb[s.x * 3 + 0]; o1.x = cb[s.x * 3 + 1]; o2.x = cb[s.x * 3 + 2];
    o0.y = cb[s.y * 3 + 0]; o1.y = cb[s.y * 3 + 1]; o2.y = cb[s.y * 3 + 2];
    o0.z = cb[s.z * 3 + 0]; o1.z = cb[s.z * 3 + 1]; o2.z = cb[s.z * 3 + 2];
    o0.w = cb[s.w * 3 + 0]; o1.w = cb[s.w * 3 + 1]; o2.w = cb[s.w * 3 + 2];
    ((float4*)(out + ((size_t)b * 3 + 0) * N_PIX))[p4] = o0;
    ((float4*)(out + ((size_t)b * 3 + 1) * N_PIX))[p4] = o1;
    ((float4*)(out + ((size_t)b * 3 + 2) * N_PIX))[p4] = o2;
}

// ---------------------------------------------------------------------------
extern "C" void kernel_launch(void* const* d_in, const int* in_sizes, int n_in,
                              void* d_out, int out_size, void* d_ws, size_t ws_size,
                              hipStream_t stream)
{
    (void)in_sizes; (void)n_in; (void)out_size; (void)ws_size;
    const float* z      = (const float*)d_in[0];
    const float* images = (const float*)d_in[1];
    const int*   seg    = (const int*)d_in[2];
    const float* A      = (const float*)d_in[3];
    const float* proj_w = (const float*)d_in[4];
    const float* proj_b = (const float*)d_in[5];
    const float* blk_w  = (const float*)d_in[6];
    const float* blk_b  = (const float*)d_in[7];
    const float* ada_w1 = (const float*)d_in[8];
    const float* ada_b1 = (const float*)d_in[9];
    const float* ada_w2 = (const float*)d_in[10];
    const float* ada_b2 = (const float*)d_in[11];
    const float* rgb_w  = (const float*)d_in[12];
    const float* rgb_b  = (const float*)d_in[13];
    float* out = (float*)d_out;

    float* ws = (float*)d_ws;
    float* mv       = ws;                   // 18432 (zeroed)
    float* sumabar  = ws + 18432;           // 16   (zeroed)
    float* abar     = ws + 18448;           // 8192
    float* style    = ws + 26640;           // 4096
    float* colr     = ws + 30736;           // 24576
    float* wpad     = ws + 55312;           // 36864
    float* xin      = ws + 92176;           // 1179648 -> 1271824
    float* x        = ws + 1271824;         // 2097152 -> 3368976
    unsigned short* xh    = (unsigned short*)(ws + 3368976);
    unsigned short* xl    = (unsigned short*)(ws + 4417552);
    unsigned short* h1t_h = (unsigned short*)(ws + 5466128);
    unsigned short* h1t_l = (unsigned short*)(ws + 6514704);
    unsigned short* Ah    = (unsigned short*)(ws + 7563280);
    unsigned short* Al    = (unsigned short*)(ws + 11757584);
    unsigned short* Wh    = (unsigned short*)(ws + 15951888);
    unsigned short* Wl    = (unsigned short*)(ws + 16214032);
    float* seg_slab = ws + 16476176;        // 1048576 -> 17524752
    float* A_slab   = ws + 17524752;        // 262144  -> 17786896

    const float sc_in = (float)sqrt(2.0 / 131.0);
    const float sc_c  = (float)sqrt(2.0 / 256.0);
    const float sc_2c = (float)sqrt(2.0 / 512.0);

    (void)hipMemsetAsync(mv, 0, 18448 * sizeof(float), stream);
    prep_all_kernel<<<dim3(641), 1024, 0, stream>>>(
        images, seg, seg_slab, A, Ah, Al, A_slab,
        blk_w, Wh, Wl, sc_c, proj_w, wpad);
    prep_xin_kernel<<<dim3(4640), 256, 0, stream>>>(
        seg_slab, A_slab, z, xin, abar, sumabar);

    gemm_nt_kernel<<<dim3(128, 4), 256, 0, stream>>>(xin, wpad, x, 144, sc_in, proj_b,
                                                     abar, mv, xh, xl);

    for (int i = 0; i < 8; ++i) {
        gemm_nt_mfma_kernel<<<dim3(64, 5), 512, 0, stream>>>(
            xh, xl, Wh + (size_t)i * 65536, Wl + (size_t)i * 65536,
            blk_b + i * CDIM, h1t_h, h1t_l,
            mv + i * 2048, sumabar, blk_w + (size_t)i * CDIM * CDIM,
            ada_w1 + (size_t)i * 512 * 256, ada_b1 + i * 512,
            ada_w2 + (size_t)i * 512 * 512, ada_b2 + i * 512,
            style, sc_c, sc_2c);
        const bool last = (i == 7);
        gemm_nn_mfma_kernel<<<dim3(16, 2, 8), 512, 0, stream>>>(
            Ah, Al, h1t_h, h1t_l, style, abar,
            last ? x : nullptr,
            last ? nullptr : xh, last ? nullptr : xl,
            last ? nullptr : (mv + (i + 1) * 2048));
    }

    color_kernel<<<dim3(2048), 256, 0, stream>>>(x, rgb_w, rgb_b, colr, sc_c);
    gather_kernel<<<dim3(2048), 256, 0, stream>>>(seg, colr, out);
}

// Round 12
// 549.078 us; speedup vs baseline: 1.0092x; 1.0092x over previous
//
#include <hip/hip_runtime.h>
#include <math.h>

#define N_PIX (512*512)
#define S_SEG 1024
#define CDIM  256
#define BATCH 8

typedef __attribute__((ext_vector_type(4))) float f32x4;
typedef __attribute__((ext_vector_type(8))) short bf16x8;
typedef __fp16 half2v __attribute__((ext_vector_type(2)));
typedef __attribute__((address_space(3))) unsigned int lds_uint;

__device__ __forceinline__ float lrelu(float v) { return v > 0.f ? v : 0.2f * v; }

__device__ __forceinline__ unsigned short bf16_hi(float x) {
    union { float f; unsigned int u; } v; v.f = x;
    unsigned int r = v.u + 0x7FFFu + ((v.u >> 16) & 1u);
    return (unsigned short)(r >> 16);
}
__device__ __forceinline__ float bf16_tof(unsigned short h) {
    union { float f; unsigned int u; } v; v.u = ((unsigned int)h) << 16;
    return v.f;
}
__device__ __forceinline__ float dot4(float4 a, float4 b) {
    return a.x * b.x + a.y * b.y + a.z * b.z + a.w * b.w;
}
__device__ __forceinline__ unsigned pack_h2(float lo, float hi) {
    union { half2v h; unsigned u; } c;
    c.h = __builtin_amdgcn_cvt_pkrtz(lo, hi);
    return c.u;
}
__device__ __forceinline__ void ds_pk_add(lds_uint* p, unsigned val) {
    asm volatile("ds_pk_add_f16 %0, %1"
                 :: "v"((unsigned)(unsigned long)p), "v"(val) : "memory");
}

// ---------------------------------------------------------------------------
// MERGED prep, atomic-free flush. blocks:
//   [0,256)   : segment pooling -> seg_slab (LDS pk-f16 bins; ~27us LDS-atomic
//               floor: 16.8M ops / 256 CU / ~1 op/cyc)
//   [256,512) : A -> bf16 hi/lo split; col partials -> A_slab. ALL 1024
//               threads active (4 row-groups x 8 rows + LDS reduce) so this
//               branch overlaps the seg branch's atomic wall.
//   [512,640) : blk_w -> Wh/Wl split
//   640       : proj_w -> wpad
// ---------------------------------------------------------------------------
__global__ __launch_bounds__(1024) void prep_all_kernel(
    const float* __restrict__ images, const int* __restrict__ seg,
    float* __restrict__ seg_slab,
    const float* __restrict__ A, unsigned short* __restrict__ Ah,
    unsigned short* __restrict__ Al, float* __restrict__ A_slab,
    const float* __restrict__ blk_w, unsigned short* __restrict__ Wh,
    unsigned short* __restrict__ Wl, float sc_c,
    const float* __restrict__ proj_w, float* __restrict__ wpad)
{
    __shared__ unsigned int sm[4096];   // seg: 8KB bins | A-split: 16KB reduce
    const int blk = blockIdx.x;
    const int t = threadIdx.x;

    if (blk < 256) {
        const int b = blk >> 5;
        const int chunk = blk & 31;
        for (int i = t; i < S_SEG * 2; i += 1024) sm[i] = 0u;
        __syncthreads();

        lds_uint* bl2 = (lds_uint*)sm;
        const float4* imr = (const float4*)(images + (size_t)b * 3 * N_PIX);
        const float4* img = imr + N_PIX / 4;
        const float4* imb = img + N_PIX / 4;
        const int4* sg4 = (const int4*)(seg + (size_t)b * N_PIX);
        const int base4 = chunk * (N_PIX / 32 / 4);

#pragma unroll
        for (int it = 0; it < 2; ++it) {
            int p4 = base4 + it * 1024 + t;
            int4 s = sg4[p4];
            float4 r = imr[p4];
            float4 g = img[p4];
            float4 bb = imb[p4];
            ds_pk_add(bl2 + s.x * 2 + 0, pack_h2(r.x, g.x));
            ds_pk_add(bl2 + s.x * 2 + 1, pack_h2(bb.x, 1.f));
            ds_pk_add(bl2 + s.y * 2 + 0, pack_h2(r.y, g.y));
            ds_pk_add(bl2 + s.y * 2 + 1, pack_h2(bb.y, 1.f));
            ds_pk_add(bl2 + s.z * 2 + 0, pack_h2(r.z, g.z));
            ds_pk_add(bl2 + s.z * 2 + 1, pack_h2(bb.z, 1.f));
            ds_pk_add(bl2 + s.w * 2 + 0, pack_h2(r.w, g.w));
            ds_pk_add(bl2 + s.w * 2 + 1, pack_h2(bb.w, 1.f));
        }
        __syncthreads();
        if (t < S_SEG) {
            union { unsigned u; __fp16 h[2]; } p0, p1;
            p0.u = sm[t * 2 + 0];
            p1.u = sm[t * 2 + 1];
            float4 o;
            o.x = (float)p0.h[0];
            o.y = (float)p0.h[1];
            o.z = (float)p1.h[0];
            o.w = (float)p1.h[1];
            ((float4*)seg_slab)[(size_t)blk * 1024 + t] = o;
        }
        return;
    }

    if (blk < 512) {
        // ---- A split, 1024 threads: col = t&255, row-group = t>>8 (8 rows) --
        const int ablk = blk - 256;
        const int b = ablk >> 5;
        const int chunk = ablk & 31;
        const int col = t & 255;
        const int rg = t >> 8;
        const size_t base4 = (((size_t)b * 1024 * 1024 + (size_t)chunk * 32 * 1024) >> 2)
                             + (size_t)rg * 8 * 256;
        const float4* Af = ((const float4*)A) + base4;
        ushort4* Ahf = ((ushort4*)Ah) + base4;
        ushort4* Alf = ((ushort4*)Al) + base4;
        float a0 = 0.f, a1 = 0.f, a2 = 0.f, a3 = 0.f;
#pragma unroll
        for (int r = 0; r < 8; ++r) {
            float4 v = Af[r * 256 + col];
            ushort4 h, l;
            h.x = bf16_hi(v.x); l.x = bf16_hi(v.x - bf16_tof(h.x));
            h.y = bf16_hi(v.y); l.y = bf16_hi(v.y - bf16_tof(h.y));
            h.z = bf16_hi(v.z); l.z = bf16_hi(v.z - bf16_tof(h.z));
            h.w = bf16_hi(v.w); l.w = bf16_hi(v.w - bf16_tof(h.w));
            Ahf[r * 256 + col] = h;
            Alf[r * 256 + col] = l;
            a0 += v.x; a1 += v.y; a2 += v.z; a3 += v.w;
        }
        float4* red4 = (float4*)sm;
        float4 p; p.x = a0; p.y = a1; p.z = a2; p.w = a3;
        red4[rg * 256 + col] = p;
        __syncthreads();
        if (t < 256) {
            float4 s0 = red4[t], s1 = red4[256 + t], s2 = red4[512 + t], s3 = red4[768 + t];
            float4 o;
            o.x = s0.x + s1.x + s2.x + s3.x;
            o.y = s0.y + s1.y + s2.y + s3.y;
            o.z = s0.z + s1.z + s2.z + s3.z;
            o.w = s0.w + s1.w + s2.w + s3.w;
            ((float4*)A_slab)[(size_t)ablk * 256 + t] = o;
        }
        return;
    }

    if (blk < 640) {
        unsigned int idx = (blk - 512) * 1024 + t;
        float4 v = ((const float4*)blk_w)[idx];
        ushort4 h, l;
        float a;
        a = v.x * sc_c; h.x = bf16_hi(a); l.x = bf16_hi(a - bf16_tof(h.x));
        a = v.y * sc_c; h.y = bf16_hi(a); l.y = bf16_hi(a - bf16_tof(h.y));
        a = v.z * sc_c; h.z = bf16_hi(a); l.z = bf16_hi(a - bf16_tof(h.z));
        a = v.w * sc_c; h.w = bf16_hi(a); l.w = bf16_hi(a - bf16_tof(h.w));
        ((ushort4*)Wh)[idx] = h;
        ((ushort4*)Wl)[idx] = l;
        return;
    }

    for (int i = t; i < 256 * 144; i += 1024) {
        int n = i / 144, k = i % 144;
        wpad[i] = (k < 131) ? proj_w[n * 131 + k] : 0.f;
    }
}

// ---------------------------------------------------------------------------
// prep_xin + slab reductions (unchanged from R11)
// ---------------------------------------------------------------------------
__global__ __launch_bounds__(256) void prep_xin_kernel(
    const float* __restrict__ seg_slab, const float* __restrict__ A_slab,
    const float* __restrict__ z, float* __restrict__ xin,
    float* __restrict__ abar, float* __restrict__ sumabar)
{
    const int t = threadIdx.x;
    if (blockIdx.x >= 4608) {
        int idx = (blockIdx.x - 4608) * 256 + t;
        int b = idx >> 10, s = idx & 1023;
        float acc = 0.f;
        const float* sl = A_slab + (size_t)(b << 5) * 1024 + s;
#pragma unroll 8
        for (int ch = 0; ch < 32; ++ch) acc += sl[ch * 1024];
        float v = acc * (1.f / 1024.f);
        abar[idx] = v;
        __shared__ float red[256];
        red[t] = v;
        __syncthreads();
        for (int off = 128; off > 0; off >>= 1) {
            if (t < off) red[t] += red[t + off];
            __syncthreads();
        }
        if (t == 0) atomicAdd(&sumabar[b], red[0]);
        return;
    }

    int idx = blockIdx.x * 256 + t;
    int r = idx / 144, c = idx % 144;
    int b = r >> 10;
    float v;
    if (c < 3) {
        int s = r & 1023;
        const float4* sl = (const float4*)seg_slab + (size_t)(b << 5) * 1024 + s;
        float cnt = 0.f, sc = 0.f;
#pragma unroll 8
        for (int ch = 0; ch < 32; ++ch) {
            float4 w = sl[ch * 1024];
            cnt += w.w;
            sc += (c == 0) ? w.x : ((c == 1) ? w.y : w.z);
        }
        v = sc / (cnt + 1e-6f);
    } else if (c < 131) {
        v = z[b * 128 + (c - 3)];
    } else {
        v = 0.f;
    }
    xin[idx] = v;
}

// ---------------------------------------------------------------------------
// staging helpers (rule #21 both-sides swizzle); T = block thread count
// ---------------------------------------------------------------------------
__device__ __forceinline__ void stage_tile(
    const unsigned short* __restrict__ g, int grow,
    unsigned short* lds, int tid, int nissue, int T)
{
    for (int i = 0; i < nissue; ++i) {
        int c = i * T + tid;
        int row = c >> 3, cin = c & 7;
        int cs = cin ^ (row & 7);
        const unsigned short* src = g + (size_t)row * grow + cs * 8;
        unsigned short* dst = lds + (size_t)(i * T + (tid & ~63)) * 8;
        __builtin_amdgcn_global_load_lds(
            (const __attribute__((address_space(1))) unsigned int*)src,
            (__attribute__((address_space(3))) unsigned int*)dst, 16, 0, 0);
    }
}

__device__ __forceinline__ int frag_idx(int row, int ks, int l)
{
    int chunk = (ks * 4 + (l >> 4)) ^ (row & 7);
    return row * 64 + chunk * 8;
}

// ---------------------------------------------------------------------------
// MFMA split-3 GEMM: x_out = lrelu(gamma*(A @ h1) + beta) + optional outputs.
// Tile 64x128, 512 thr / 8 waves. 1-D grid of 256 blocks with XCD-aware
// mapping (T1): xcd = bid&7 owns 2 (bn,b) pairs; the 16 blocks sharing a
// (bn,b) B-slice (512KB, L2-fits) land on one XCD -> B reads become L2-hits.
// ---------------------------------------------------------------------------
__global__ __launch_bounds__(512) void gemm_nn_mfma_kernel(
    const unsigned short* __restrict__ Ah_g, const unsigned short* __restrict__ Al_g,
    const unsigned short* __restrict__ Hh_g, const unsigned short* __restrict__ Hl_g,
    const float* __restrict__ style, const float* __restrict__ abar,
    float* __restrict__ x, unsigned short* __restrict__ xh,
    unsigned short* __restrict__ xl, float* __restrict__ mv)
{
    __shared__ __align__(16) unsigned short Ah_s[64 * 64];
    __shared__ __align__(16) unsigned short Al_s[64 * 64];
    __shared__ __align__(16) unsigned short Bh_s[128 * 64];
    __shared__ __align__(16) unsigned short Bl_s[128 * 64];
    __shared__ float mvred[128];
    const int tid = threadIdx.x;
    const int bid = blockIdx.x;
    const int xcd = bid & 7;
    const int j = bid >> 3;                 // 0..31
    const int pairidx = (xcd << 1) | (j >> 4);  // 0..15
    const int bm = j & 15;
    const int bn = pairidx & 1;
    const int b = pairidx >> 1;
    const int l = tid & 63, wave = tid >> 6;
    const int wr = wave >> 2, wc = wave & 3;
    if (mv && tid < 128) mvred[tid] = 0.f;

    const unsigned short* Ag_h = Ah_g + ((size_t)(b * 1024 + bm * 64)) * 1024;
    const unsigned short* Ag_l = Al_g + ((size_t)(b * 1024 + bm * 64)) * 1024;
    const unsigned short* Hg_h = Hh_g + ((size_t)(b * 256 + bn * 128)) * 1024;
    const unsigned short* Hg_l = Hl_g + ((size_t)(b * 256 + bn * 128)) * 1024;

    f32x4 acc[2][2];
#pragma unroll
    for (int i = 0; i < 2; ++i)
#pragma unroll
        for (int jj = 0; jj < 2; ++jj) acc[i][jj] = (f32x4){0.f, 0.f, 0.f, 0.f};

    for (int kt = 0; kt < 16; ++kt) {
        stage_tile(Ag_h + kt * 64, 1024, Ah_s, tid, 1, 512);
        stage_tile(Ag_l + kt * 64, 1024, Al_s, tid, 1, 512);
        stage_tile(Hg_h + kt * 64, 1024, Bh_s, tid, 2, 512);
        stage_tile(Hg_l + kt * 64, 1024, Bl_s, tid, 2, 512);
        __syncthreads();
#pragma unroll
        for (int ks = 0; ks < 2; ++ks) {
            bf16x8 ah[2], al[2], bh[2], bl[2];
#pragma unroll
            for (int fm = 0; fm < 2; ++fm) {
                int row = wr * 32 + fm * 16 + (l & 15);
                int idx = frag_idx(row, ks, l);
                ah[fm] = *(const bf16x8*)&Ah_s[idx];
                al[fm] = *(const bf16x8*)&Al_s[idx];
            }
#pragma unroll
            for (int fn = 0; fn < 2; ++fn) {
                int row = wc * 32 + fn * 16 + (l & 15);
                int idx = frag_idx(row, ks, l);
                bh[fn] = *(const bf16x8*)&Bh_s[idx];
                bl[fn] = *(const bf16x8*)&Bl_s[idx];
            }
#pragma unroll
            for (int fm = 0; fm < 2; ++fm)
#pragma unroll
                for (int fn = 0; fn < 2; ++fn) {
                    acc[fm][fn] = __builtin_amdgcn_mfma_f32_16x16x32_bf16(ah[fm], bh[fn], acc[fm][fn], 0, 0, 0);
                    acc[fm][fn] = __builtin_amdgcn_mfma_f32_16x16x32_bf16(ah[fm], bl[fn], acc[fm][fn], 0, 0, 0);
                    acc[fm][fn] = __builtin_amdgcn_mfma_f32_16x16x32_bf16(al[fm], bh[fn], acc[fm][fn], 0, 0, 0);
                }
        }
        __syncthreads();
    }

    const float* st = style + b * 2 * CDIM;
#pragma unroll
    for (int fn = 0; fn < 2; ++fn) {
        int col = bn * 128 + wc * 32 + fn * 16 + (l & 15);
        float ga = st[col], be = st[CDIM + col];
        float pmv = 0.f;
#pragma unroll
        for (int fm = 0; fm < 2; ++fm) {
            int m0 = bm * 64 + wr * 32 + fm * 16 + (l >> 4) * 4;
#pragma unroll
            for (int r = 0; r < 4; ++r) {
                float v = lrelu(ga * acc[fm][fn][r] + be);
                size_t off = ((size_t)(b * 1024 + m0 + r)) * 256 + col;
                if (x) x[off] = v;
                if (xh) {
                    unsigned short h = bf16_hi(v);
                    xh[off] = h;
                    xl[off] = bf16_hi(v - bf16_tof(h));
                }
                pmv += abar[b * 1024 + m0 + r] * v;
            }
        }
        if (mv) atomicAdd(&mvred[wc * 32 + fn * 16 + (l & 15)], pmv);
    }
    if (mv) {
        __syncthreads();
        if (tid < 128) atomicAdd(&mv[b * 256 + bn * 128 + tid], mvred[tid]);
    }
}

// ---------------------------------------------------------------------------
// MFMA split-3 GEMM (h1 = x @ W'^T + b, transposed bf16 output), 512 thr /
// 8 waves, PLUS the per-batch style MLP at blockIdx.y == 4 (wave-per-output).
// ---------------------------------------------------------------------------
__global__ __launch_bounds__(512) void gemm_nt_mfma_kernel(
    const unsigned short* __restrict__ xh_g, const unsigned short* __restrict__ xl_g,
    const unsigned short* __restrict__ Wh, const unsigned short* __restrict__ Wl,
    const float* __restrict__ bias,
    unsigned short* __restrict__ h1t_h, unsigned short* __restrict__ h1t_l,
    const float* __restrict__ mv, const float* __restrict__ sumabar,
    const float* __restrict__ Wblk_f,
    const float* __restrict__ W1, const float* __restrict__ b1,
    const float* __restrict__ W2, const float* __restrict__ b2,
    float* __restrict__ style, float sc_c, float sc_2c)
{
    __shared__ __align__(16) unsigned short Ah_s[128 * 64];
    __shared__ __align__(16) unsigned short Al_s[128 * 64];
    __shared__ __align__(16) unsigned short Bh_s[64 * 64];
    __shared__ __align__(16) unsigned short Bl_s[64 * 64];
    const int tid = threadIdx.x;
    const int bm = blockIdx.x, bn = blockIdx.y;

    if (bn == 4) {
        if (bm >= BATCH * 4) return;
        const int bb = bm >> 2;
        const int q = bm & 3;
        const int w = tid >> 6, lane = tid & 63;
        float* m_s = (float*)Ah_s;
        float* s1_s = (float*)Bh_s;

        const float4 mvreg = *(const float4*)&mv[bb * 256 + lane * 4];
        const float sab = sumabar[bb];

        for (int g = 0; g < 4; ++g) {
            const int o0 = w * 32 + g * 8;
            float p[8];
#pragma unroll
            for (int jj = 0; jj < 8; ++jj) {
                const float4 wv = *(const float4*)&Wblk_f[(size_t)(o0 + jj) * 256 + lane * 4];
                p[jj] = dot4(wv, mvreg);
            }
#pragma unroll
            for (int off = 32; off > 0; off >>= 1)
#pragma unroll
                for (int jj = 0; jj < 8; ++jj) p[jj] += __shfl_xor(p[jj], off);
            if (lane == 0)
#pragma unroll
                for (int jj = 0; jj < 8; ++jj)
                    m_s[o0 + jj] = sc_c * p[jj] + sab * bias[o0 + jj];
        }
        __syncthreads();
        const float4 mreg = *(const float4*)&m_s[lane * 4];

        for (int g = 0; g < 8; ++g) {
            const int o0 = w * 64 + g * 8;
            float p[8];
#pragma unroll
            for (int jj = 0; jj < 8; ++jj) {
                const float4 wv = *(const float4*)&W1[(size_t)(o0 + jj) * 256 + lane * 4];
                p[jj] = dot4(wv, mreg);
            }
#pragma unroll
            for (int off = 32; off > 0; off >>= 1)
#pragma unroll
                for (int jj = 0; jj < 8; ++jj) p[jj] += __shfl_xor(p[jj], off);
            if (lane == 0)
#pragma unroll
                for (int jj = 0; jj < 8; ++jj)
                    s1_s[o0 + jj] = lrelu(sc_c * p[jj] + b1[o0 + jj]);
        }
        __syncthreads();
        const float4 sa = *(const float4*)&s1_s[lane * 4];
        const float4 sb = *(const float4*)&s1_s[256 + lane * 4];

        for (int g = 0; g < 2; ++g) {
            const int o0 = q * 128 + w * 16 + g * 8;
            float p[8];
#pragma unroll
            for (int jj = 0; jj < 8; ++jj) {
                const float4 wa = *(const float4*)&W2[(size_t)(o0 + jj) * 512 + lane * 4];
                const float4 wb = *(const float4*)&W2[(size_t)(o0 + jj) * 512 + 256 + lane * 4];
                p[jj] = dot4(wa, sa) + dot4(wb, sb);
            }
#pragma unroll
            for (int off = 32; off > 0; off >>= 1)
#pragma unroll
                for (int jj = 0; jj < 8; ++jj) p[jj] += __shfl_xor(p[jj], off);
            if (lane == 0)
#pragma unroll
                for (int jj = 0; jj < 8; ++jj)
                    style[bb * 512 + o0 + jj] = sc_2c * p[jj] + b2[o0 + jj];
        }
        return;
    }

    // ---- GEMM path (8 waves, wave-tile 64x16) ----
    const int l = tid & 63, wave = tid >> 6;
    const int wr = wave >> 2, wc = wave & 3;
    const int row0 = bm * 128;
    const int b = row0 >> 10;

    const unsigned short* Ag_h = xh_g + (size_t)row0 * 256;
    const unsigned short* Ag_l = xl_g + (size_t)row0 * 256;
    const unsigned short* Bg_h = Wh + (size_t)(bn * 64) * 256;
    const unsigned short* Bg_l = Wl + (size_t)(bn * 64) * 256;

    f32x4 acc[4];
#pragma unroll
    for (int i = 0; i < 4; ++i) acc[i] = (f32x4){0.f, 0.f, 0.f, 0.f};

    for (int kt = 0; kt < 4; ++kt) {
        stage_tile(Ag_h + kt * 64, 256, Ah_s, tid, 2, 512);
        stage_tile(Ag_l + kt * 64, 256, Al_s, tid, 2, 512);
        stage_tile(Bg_h + kt * 64, 256, Bh_s, tid, 1, 512);
        stage_tile(Bg_l + kt * 64, 256, Bl_s, tid, 1, 512);
        __syncthreads();
#pragma unroll
        for (int ks = 0; ks < 2; ++ks) {
            bf16x8 ah[4], al[4], bh, bl;
#pragma unroll
            for (int fm = 0; fm < 4; ++fm) {
                int row = wr * 64 + fm * 16 + (l & 15);
                int idx = frag_idx(row, ks, l);
                ah[fm] = *(const bf16x8*)&Ah_s[idx];
                al[fm] = *(const bf16x8*)&Al_s[idx];
            }
            {
                int row = wc * 16 + (l & 15);
                int idx = frag_idx(row, ks, l);
                bh = *(const bf16x8*)&Bh_s[idx];
                bl = *(const bf16x8*)&Bl_s[idx];
            }
#pragma unroll
            for (int fm = 0; fm < 4; ++fm) {
                acc[fm] = __builtin_amdgcn_mfma_f32_16x16x32_bf16(ah[fm], bh, acc[fm], 0, 0, 0);
                acc[fm] = __builtin_amdgcn_mfma_f32_16x16x32_bf16(ah[fm], bl, acc[fm], 0, 0, 0);
                acc[fm] = __builtin_amdgcn_mfma_f32_16x16x32_bf16(al[fm], bh, acc[fm], 0, 0, 0);
            }
        }
        __syncthreads();
    }

    {
        int col = bn * 64 + wc * 16 + (l & 15);
        float bi = bias[col];
#pragma unroll
        for (int fm = 0; fm < 4; ++fm) {
            int s0 = (row0 & 1023) + wr * 64 + fm * 16 + (l >> 4) * 4;
            float v0 = acc[fm][0] + bi;
            float v1 = acc[fm][1] + bi;
            float v2 = acc[fm][2] + bi;
            float v3 = acc[fm][3] + bi;
            ushort4 hv, lv;
            hv.x = bf16_hi(v0); lv.x = bf16_hi(v0 - bf16_tof(hv.x));
            hv.y = bf16_hi(v1); lv.y = bf16_hi(v1 - bf16_tof(hv.y));
            hv.z = bf16_hi(v2); lv.z = bf16_hi(v2 - bf16_tof(hv.z));
            hv.w = bf16_hi(v3); lv.w = bf16_hi(v3 - bf16_tof(hv.w));
            size_t off = ((size_t)(b * 256 + col)) * 1024 + s0;
            *(ushort4*)&h1t_h[off] = hv;
            *(ushort4*)&h1t_l[off] = lv;
        }
    }
}

// ---------------------------------------------------------------------------
// fp32 VALU gemm_nt (proj only) + mv + bf16 emit
// ---------------------------------------------------------------------------
#define BM 64
#define BN 64
#define BK 16
__global__ __launch_bounds__(256) void gemm_nt_kernel(
    const float* __restrict__ A, const float* __restrict__ B,
    float* __restrict__ C, int K, float alpha, const float* __restrict__ bias,
    const float* __restrict__ abar, float* __restrict__ mv,
    unsigned short* __restrict__ xh, unsigned short* __restrict__ xl)
{
    __shared__ float As[BK][BM + 4];
    __shared__ float Bs[BK][BN + 4];
    __shared__ float red[16][BN];
    const int tid = threadIdx.x;
    const int bm = blockIdx.x, bn = blockIdx.y;
    const int tx = tid & 15, ty = tid >> 4;
    const int lrow = tid >> 2;
    const int lk = (tid & 3) << 2;
    const float* Ag = A + (size_t)(bm * BM + lrow) * K + lk;
    const float* Bg = B + (size_t)(bn * BN + lrow) * K + lk;
    float acc[4][4] = {};

    for (int k0 = 0; k0 < K; k0 += BK) {
        float4 av = *(const float4*)(Ag + k0);
        float4 bv = *(const float4*)(Bg + k0);
        __syncthreads();
        As[lk + 0][lrow] = av.x; As[lk + 1][lrow] = av.y;
        As[lk + 2][lrow] = av.z; As[lk + 3][lrow] = av.w;
        Bs[lk + 0][lrow] = bv.x; Bs[lk + 1][lrow] = bv.y;
        Bs[lk + 2][lrow] = bv.z; Bs[lk + 3][lrow] = bv.w;
        __syncthreads();
#pragma unroll
        for (int kk = 0; kk < BK; ++kk) {
            const float4 a = *(const float4*)&As[kk][ty << 2];
            const float4 b = *(const float4*)&Bs[kk][tx << 2];
            float ar[4] = {a.x, a.y, a.z, a.w};
            float br[4] = {b.x, b.y, b.z, b.w};
#pragma unroll
            for (int i = 0; i < 4; ++i)
#pragma unroll
                for (int jj = 0; jj < 4; ++jj)
                    acc[i][jj] += ar[i] * br[jj];
        }
    }
    const int row = bm * BM + (ty << 2);
    const int col = bn * BN + (tx << 2);
    const int b = row >> 10;
    float bi[4] = {bias[col], bias[col + 1], bias[col + 2], bias[col + 3]};
    float o[4][4];
#pragma unroll
    for (int i = 0; i < 4; ++i) {
        float4 ov;
        ov.x = o[i][0] = alpha * acc[i][0] + bi[0];
        ov.y = o[i][1] = alpha * acc[i][1] + bi[1];
        ov.z = o[i][2] = alpha * acc[i][2] + bi[2];
        ov.w = o[i][3] = alpha * acc[i][3] + bi[3];
        *(float4*)(C + (size_t)(row + i) * CDIM + col) = ov;
#pragma unroll
        for (int jj = 0; jj < 4; ++jj) {
            size_t off = (size_t)(row + i) * CDIM + col + jj;
            unsigned short h = bf16_hi(o[i][jj]);
            xh[off] = h;
            xl[off] = bf16_hi(o[i][jj] - bf16_tof(h));
        }
    }
    {
        float p[4];
#pragma unroll
        for (int jj = 0; jj < 4; ++jj) {
            p[jj] = 0.f;
#pragma unroll
            for (int i = 0; i < 4; ++i)
                p[jj] += abar[((row + i) & 1023) + (b << 10)] * o[i][jj];
            red[ty][(tx << 2) + jj] = p[jj];
        }
        __syncthreads();
        if (tid < BN) {
            float s = 0.f;
#pragma unroll
            for (int tt = 0; tt < 16; ++tt) s += red[tt][tid];
            atomicAdd(&mv[b * CDIM + bn * BN + tid], s);
        }
    }
}

// ---------------------------------------------------------------------------
// color: writes tanh'd color table
// ---------------------------------------------------------------------------
__global__ __launch_bounds__(256) void color_kernel(
    const float* __restrict__ x, const float* __restrict__ rgb_w,
    const float* __restrict__ rgb_b, float* __restrict__ color, float sc_c)
{
    const int wave = threadIdx.x >> 6;
    const int lane = threadIdx.x & 63;
    const int r = blockIdx.x * 4 + wave;
    const float4 xv = *(const float4*)(x + (size_t)r * CDIM + lane * 4);
    float p[3];
#pragma unroll
    for (int cc = 0; cc < 3; ++cc) {
        const float4 wv = *(const float4*)(rgb_w + cc * CDIM + lane * 4);
        p[cc] = xv.x * wv.x + xv.y * wv.y + xv.z * wv.z + xv.w * wv.w;
    }
#pragma unroll
    for (int off = 32; off > 0; off >>= 1) {
#pragma unroll
        for (int cc = 0; cc < 3; ++cc) p[cc] += __shfl_down(p[cc], off);
    }
    if (lane == 0) {
#pragma unroll
        for (int cc = 0; cc < 3; ++cc)
            color[(size_t)r * 3 + cc] = tanhf(sc_c * p[cc] + rgb_b[cc]);
    }
}

// ---------------------------------------------------------------------------
// gather: 4 pixels/thread, float4 stores per plane; color already tanh'd
// ---------------------------------------------------------------------------
__global__ __launch_bounds__(256) void gather_kernel(
    const int* __restrict__ seg, const float* __restrict__ color,
    float* __restrict__ out)
{
    int idx = blockIdx.x * 256 + threadIdx.x;
    int b = idx >> 16;
    int p4 = idx & 65535;
    int4 s = ((const int4*)(seg + (size_t)b * N_PIX))[p4];
    const float* cb = color + (size_t)b * S_SEG * 3;
    float4 o0, o1, o2;
    o0.x = cb[s.x * 3 + 0]; o1.x = cb[s.x * 3 + 1]; o2.x = cb[s.x * 3 + 2];
    o0.y = cb[s.y * 3 + 0]; o1.y = cb[s.y * 3 + 1]; o2.y = cb[s.y * 3 + 2];
    o0.z = cb[s.z * 3 + 0]; o1.z = cb[s.z * 3 + 1]; o2.z = cb[s.z * 3 + 2];
    o0.w = cb[s.w * 3 + 0]; o1.w = cb[s.w * 3 + 1]; o2.w = cb[s.w * 3 + 2];
    ((float4*)(out + ((size_t)b * 3 + 0) * N_PIX))[p4] = o0;
    ((float4*)(out + ((size_t)b * 3 + 1) * N_PIX))[p4] = o1;
    ((float4*)(out + ((size_t)b * 3 + 2) * N_PIX))[p4] = o2;
}

// ---------------------------------------------------------------------------
extern "C" void kernel_launch(void* const* d_in, const int* in_sizes, int n_in,
                              void* d_out, int out_size, void* d_ws, size_t ws_size,
                              hipStream_t stream)
{
    (void)in_sizes; (void)n_in; (void)out_size; (void)ws_size;
    const float* z      = (const float*)d_in[0];
    const float* images = (const float*)d_in[1];
    const int*   seg    = (const int*)d_in[2];
    const float* A      = (const float*)d_in[3];
    const float* proj_w = (const float*)d_in[4];
    const float* proj_b = (const float*)d_in[5];
    const float* blk_w  = (const float*)d_in[6];
    const float* blk_b  = (const float*)d_in[7];
    const float* ada_w1 = (const float*)d_in[8];
    const float* ada_b1 = (const float*)d_in[9];
    const float* ada_w2 = (const float*)d_in[10];
    const float* ada_b2 = (const float*)d_in[11];
    const float* rgb_w  = (const float*)d_in[12];
    const float* rgb_b  = (const float*)d_in[13];
    float* out = (float*)d_out;

    float* ws = (float*)d_ws;
    float* mv       = ws;                   // 18432 (zeroed)
    float* sumabar  = ws + 18432;           // 16   (zeroed)
    float* abar     = ws + 18448;           // 8192
    float* style    = ws + 26640;           // 4096
    float* colr     = ws + 30736;           // 24576
    float* wpad     = ws + 55312;           // 36864
    float* xin      = ws + 92176;           // 1179648 -> 1271824
    float* x        = ws + 1271824;         // 2097152 -> 3368976
    unsigned short* xh    = (unsigned short*)(ws + 3368976);
    unsigned short* xl    = (unsigned short*)(ws + 4417552);
    unsigned short* h1t_h = (unsigned short*)(ws + 5466128);
    unsigned short* h1t_l = (unsigned short*)(ws + 6514704);
    unsigned short* Ah    = (unsigned short*)(ws + 7563280);
    unsigned short* Al    = (unsigned short*)(ws + 11757584);
    unsigned short* Wh    = (unsigned short*)(ws + 15951888);
    unsigned short* Wl    = (unsigned short*)(ws + 16214032);
    float* seg_slab = ws + 16476176;        // 1048576 -> 17524752
    float* A_slab   = ws + 17524752;        // 262144  -> 17786896

    const float sc_in = (float)sqrt(2.0 / 131.0);
    const float sc_c  = (float)sqrt(2.0 / 256.0);
    const float sc_2c = (float)sqrt(2.0 / 512.0);

    (void)hipMemsetAsync(mv, 0, 18448 * sizeof(float), stream);
    prep_all_kernel<<<dim3(641), 1024, 0, stream>>>(
        images, seg, seg_slab, A, Ah, Al, A_slab,
        blk_w, Wh, Wl, sc_c, proj_w, wpad);
    prep_xin_kernel<<<dim3(4640), 256, 0, stream>>>(
        seg_slab, A_slab, z, xin, abar, sumabar);

    gemm_nt_kernel<<<dim3(128, 4), 256, 0, stream>>>(xin, wpad, x, 144, sc_in, proj_b,
                                                     abar, mv, xh, xl);

    for (int i = 0; i < 8; ++i) {
        gemm_nt_mfma_kernel<<<dim3(64, 5), 512, 0, stream>>>(
            xh, xl, Wh + (size_t)i * 65536, Wl + (size_t)i * 65536,
            blk_b + i * CDIM, h1t_h, h1t_l,
            mv + i * 2048, sumabar, blk_w + (size_t)i * CDIM * CDIM,
            ada_w1 + (size_t)i * 512 * 256, ada_b1 + i * 512,
            ada_w2 + (size_t)i * 512 * 512, ada_b2 + i * 512,
            style, sc_c, sc_2c);
        const bool last = (i == 7);
        gemm_nn_mfma_kernel<<<dim3(256), 512, 0, stream>>>(
            Ah, Al, h1t_h, h1t_l, style, abar,
            last ? x : nullptr,
            last ? nullptr : xh, last ? nullptr : xl,
            last ? nullptr : (mv + (i + 1) * 2048));
    }

    color_kernel<<<dim3(2048), 256, 0, stream>>>(x, rgb_w, rgb_b, colr, sc_c);
    gather_kernel<<<dim3(2048), 256, 0, stream>>>(seg, colr, out);
}

// Round 14
// 514.779 us; speedup vs baseline: 1.0765x; 1.0666x over previous
//
#include <hip/hip_runtime.h>
#include <math.h>

#define N_PIX (512*512)
#define S_SEG 1024
#define CDIM  256
#define BATCH 8

typedef __attribute__((ext_vector_type(4))) float f32x4;
typedef __attribute__((ext_vector_type(8))) short bf16x8;
typedef __fp16 half2v __attribute__((ext_vector_type(2)));
typedef __attribute__((address_space(3))) unsigned int lds_uint;

__device__ __forceinline__ float lrelu(float v) { return v > 0.f ? v : 0.2f * v; }

__device__ __forceinline__ unsigned short bf16_hi(float x) {
    union { float f; unsigned int u; } v; v.f = x;
    unsigned int r = v.u + 0x7FFFu + ((v.u >> 16) & 1u);
    return (unsigned short)(r >> 16);
}
__device__ __forceinline__ float bf16_tof(unsigned short h) {
    union { float f; unsigned int u; } v; v.u = ((unsigned int)h) << 16;
    return v.f;
}
__device__ __forceinline__ float dot4(float4 a, float4 b) {
    return a.x * b.x + a.y * b.y + a.z * b.z + a.w * b.w;
}
__device__ __forceinline__ unsigned pack_h2(float lo, float hi) {
    union { half2v h; unsigned u; } c;
    c.h = __builtin_amdgcn_cvt_pkrtz(lo, hi);
    return c.u;
}
__device__ __forceinline__ void ds_pk_add(lds_uint* p, unsigned val) {
    asm volatile("ds_pk_add_f16 %0, %1"
                 :: "v"((unsigned)(unsigned long)p), "v"(val) : "memory");
}

// ---------------------------------------------------------------------------
// MERGED prep, atomic-free flush. A now split to Ah ONLY (plain bf16 for the
// gemm_nn A-operand; error budget analysis: absmax ~3e-11 vs 2.2e-10 thr).
// ---------------------------------------------------------------------------
__global__ __launch_bounds__(1024) void prep_all_kernel(
    const float* __restrict__ images, const int* __restrict__ seg,
    float* __restrict__ seg_slab,
    const float* __restrict__ A, unsigned short* __restrict__ Ah,
    float* __restrict__ A_slab,
    const float* __restrict__ blk_w, unsigned short* __restrict__ Wh,
    unsigned short* __restrict__ Wl, float sc_c,
    const float* __restrict__ proj_w, float* __restrict__ wpad)
{
    __shared__ unsigned int sm[4096];
    const int blk = blockIdx.x;
    const int t = threadIdx.x;

    if (blk < 256) {
        const int b = blk >> 5;
        const int chunk = blk & 31;
        for (int i = t; i < S_SEG * 2; i += 1024) sm[i] = 0u;
        __syncthreads();

        lds_uint* bl2 = (lds_uint*)sm;
        const float4* imr = (const float4*)(images + (size_t)b * 3 * N_PIX);
        const float4* img = imr + N_PIX / 4;
        const float4* imb = img + N_PIX / 4;
        const int4* sg4 = (const int4*)(seg + (size_t)b * N_PIX);
        const int base4 = chunk * (N_PIX / 32 / 4);

#pragma unroll
        for (int it = 0; it < 2; ++it) {
            int p4 = base4 + it * 1024 + t;
            int4 s = sg4[p4];
            float4 r = imr[p4];
            float4 g = img[p4];
            float4 bb = imb[p4];
            ds_pk_add(bl2 + s.x * 2 + 0, pack_h2(r.x, g.x));
            ds_pk_add(bl2 + s.x * 2 + 1, pack_h2(bb.x, 1.f));
            ds_pk_add(bl2 + s.y * 2 + 0, pack_h2(r.y, g.y));
            ds_pk_add(bl2 + s.y * 2 + 1, pack_h2(bb.y, 1.f));
            ds_pk_add(bl2 + s.z * 2 + 0, pack_h2(r.z, g.z));
            ds_pk_add(bl2 + s.z * 2 + 1, pack_h2(bb.z, 1.f));
            ds_pk_add(bl2 + s.w * 2 + 0, pack_h2(r.w, g.w));
            ds_pk_add(bl2 + s.w * 2 + 1, pack_h2(bb.w, 1.f));
        }
        __syncthreads();
        if (t < S_SEG) {
            union { unsigned u; __fp16 h[2]; } p0, p1;
            p0.u = sm[t * 2 + 0];
            p1.u = sm[t * 2 + 1];
            float4 o;
            o.x = (float)p0.h[0];
            o.y = (float)p0.h[1];
            o.z = (float)p1.h[0];
            o.w = (float)p1.h[1];
            ((float4*)seg_slab)[(size_t)blk * 1024 + t] = o;
        }
        return;
    }

    if (blk < 512) {
        const int ablk = blk - 256;
        const int b = ablk >> 5;
        const int chunk = ablk & 31;
        const int col = t & 255;
        const int rg = t >> 8;
        const size_t base4 = (((size_t)b * 1024 * 1024 + (size_t)chunk * 32 * 1024) >> 2)
                             + (size_t)rg * 8 * 256;
        const float4* Af = ((const float4*)A) + base4;
        ushort4* Ahf = ((ushort4*)Ah) + base4;
        float a0 = 0.f, a1 = 0.f, a2 = 0.f, a3 = 0.f;
#pragma unroll
        for (int r = 0; r < 8; ++r) {
            float4 v = Af[r * 256 + col];
            ushort4 h;
            h.x = bf16_hi(v.x);
            h.y = bf16_hi(v.y);
            h.z = bf16_hi(v.z);
            h.w = bf16_hi(v.w);
            Ahf[r * 256 + col] = h;
            a0 += v.x; a1 += v.y; a2 += v.z; a3 += v.w;
        }
        float4* red4 = (float4*)sm;
        float4 p; p.x = a0; p.y = a1; p.z = a2; p.w = a3;
        red4[rg * 256 + col] = p;
        __syncthreads();
        if (t < 256) {
            float4 s0 = red4[t], s1 = red4[256 + t], s2 = red4[512 + t], s3 = red4[768 + t];
            float4 o;
            o.x = s0.x + s1.x + s2.x + s3.x;
            o.y = s0.y + s1.y + s2.y + s3.y;
            o.z = s0.z + s1.z + s2.z + s3.z;
            o.w = s0.w + s1.w + s2.w + s3.w;
            ((float4*)A_slab)[(size_t)ablk * 256 + t] = o;
        }
        return;
    }

    if (blk < 640) {
        unsigned int idx = (blk - 512) * 1024 + t;
        float4 v = ((const float4*)blk_w)[idx];
        ushort4 h, l;
        float a;
        a = v.x * sc_c; h.x = bf16_hi(a); l.x = bf16_hi(a - bf16_tof(h.x));
        a = v.y * sc_c; h.y = bf16_hi(a); l.y = bf16_hi(a - bf16_tof(h.y));
        a = v.z * sc_c; h.z = bf16_hi(a); l.z = bf16_hi(a - bf16_tof(h.z));
        a = v.w * sc_c; h.w = bf16_hi(a); l.w = bf16_hi(a - bf16_tof(h.w));
        ((ushort4*)Wh)[idx] = h;
        ((ushort4*)Wl)[idx] = l;
        return;
    }

    for (int i = t; i < 256 * 144; i += 1024) {
        int n = i / 144, k = i % 144;
        wpad[i] = (k < 131) ? proj_w[n * 131 + k] : 0.f;
    }
}

// ---------------------------------------------------------------------------
// prep_xin + slab reductions (unchanged)
// ---------------------------------------------------------------------------
__global__ __launch_bounds__(256) void prep_xin_kernel(
    const float* __restrict__ seg_slab, const float* __restrict__ A_slab,
    const float* __restrict__ z, float* __restrict__ xin,
    float* __restrict__ abar, float* __restrict__ sumabar)
{
    const int t = threadIdx.x;
    if (blockIdx.x >= 4608) {
        int idx = (blockIdx.x - 4608) * 256 + t;
        int b = idx >> 10, s = idx & 1023;
        float acc = 0.f;
        const float* sl = A_slab + (size_t)(b << 5) * 1024 + s;
#pragma unroll 8
        for (int ch = 0; ch < 32; ++ch) acc += sl[ch * 1024];
        float v = acc * (1.f / 1024.f);
        abar[idx] = v;
        __shared__ float red[256];
        red[t] = v;
        __syncthreads();
        for (int off = 128; off > 0; off >>= 1) {
            if (t < off) red[t] += red[t + off];
            __syncthreads();
        }
        if (t == 0) atomicAdd(&sumabar[b], red[0]);
        return;
    }

    int idx = blockIdx.x * 256 + t;
    int r = idx / 144, c = idx % 144;
    int b = r >> 10;
    float v;
    if (c < 3) {
        int s = r & 1023;
        const float4* sl = (const float4*)seg_slab + (size_t)(b << 5) * 1024 + s;
        float cnt = 0.f, sc = 0.f;
#pragma unroll 8
        for (int ch = 0; ch < 32; ++ch) {
            float4 w = sl[ch * 1024];
            cnt += w.w;
            sc += (c == 0) ? w.x : ((c == 1) ? w.y : w.z);
        }
        v = sc / (cnt + 1e-6f);
    } else if (c < 131) {
        v = z[b * 128 + (c - 3)];
    } else {
        v = 0.f;
    }
    xin[idx] = v;
}

// ---------------------------------------------------------------------------
// staging helpers (rule #21 both-sides swizzle); T = block thread count
// ---------------------------------------------------------------------------
__device__ __forceinline__ void stage_tile(
    const unsigned short* __restrict__ g, int grow,
    unsigned short* lds, int tid, int nissue, int T)
{
    for (int i = 0; i < nissue; ++i) {
        int c = i * T + tid;
        int row = c >> 3, cin = c & 7;
        int cs = cin ^ (row & 7);
        const unsigned short* src = g + (size_t)row * grow + cs * 8;
        unsigned short* dst = lds + (size_t)(i * T + (tid & ~63)) * 8;
        __builtin_amdgcn_global_load_lds(
            (const __attribute__((address_space(1))) unsigned int*)src,
            (__attribute__((address_space(3))) unsigned int*)dst, 16, 0, 0);
    }
}

__device__ __forceinline__ int frag_idx(int row, int ks, int l)
{
    int chunk = (ks * 4 + (l >> 4)) ^ (row & 7);
    return row * 64 + chunk * 8;
}

// ---------------------------------------------------------------------------
// MFMA GEMM: x_out = lrelu(gamma*(A @ h1) + beta). A is PLAIN bf16 (Ah only,
// halves A traffic + 1/3 fewer MFMA); h1 stays hi/lo split. Tile 64x128,
// 512 thr / 8 waves, 1-D grid 256 with XCD-aware (bn,b)-slice mapping.
// ---------------------------------------------------------------------------
__global__ __launch_bounds__(512) void gemm_nn_mfma_kernel(
    const unsigned short* __restrict__ Ah_g,
    const unsigned short* __restrict__ Hh_g, const unsigned short* __restrict__ Hl_g,
    const float* __restrict__ style, const float* __restrict__ abar,
    float* __restrict__ x, unsigned short* __restrict__ xh,
    unsigned short* __restrict__ xl, float* __restrict__ mv)
{
    __shared__ __align__(16) unsigned short Ah_s[64 * 64];
    __shared__ __align__(16) unsigned short Bh_s[128 * 64];
    __shared__ __align__(16) unsigned short Bl_s[128 * 64];
    __shared__ float mvred[128];
    const int tid = threadIdx.x;
    const int bid = blockIdx.x;
    const int xcd = bid & 7;
    const int j = bid >> 3;
    const int pairidx = (xcd << 1) | (j >> 4);
    const int bm = j & 15;
    const int bn = pairidx & 1;
    const int b = pairidx >> 1;
    const int l = tid & 63, wave = tid >> 6;
    const int wr = wave >> 2, wc = wave & 3;
    if (mv && tid < 128) mvred[tid] = 0.f;

    const unsigned short* Ag_h = Ah_g + ((size_t)(b * 1024 + bm * 64)) * 1024;
    const unsigned short* Hg_h = Hh_g + ((size_t)(b * 256 + bn * 128)) * 1024;
    const unsigned short* Hg_l = Hl_g + ((size_t)(b * 256 + bn * 128)) * 1024;

    f32x4 acc[2][2];
#pragma unroll
    for (int i = 0; i < 2; ++i)
#pragma unroll
        for (int jj = 0; jj < 2; ++jj) acc[i][jj] = (f32x4){0.f, 0.f, 0.f, 0.f};

    for (int kt = 0; kt < 16; ++kt) {
        stage_tile(Ag_h + kt * 64, 1024, Ah_s, tid, 1, 512);
        stage_tile(Hg_h + kt * 64, 1024, Bh_s, tid, 2, 512);
        stage_tile(Hg_l + kt * 64, 1024, Bl_s, tid, 2, 512);
        __syncthreads();
#pragma unroll
        for (int ks = 0; ks < 2; ++ks) {
            bf16x8 ah[2], bh[2], bl[2];
#pragma unroll
            for (int fm = 0; fm < 2; ++fm) {
                int row = wr * 32 + fm * 16 + (l & 15);
                int idx = frag_idx(row, ks, l);
                ah[fm] = *(const bf16x8*)&Ah_s[idx];
            }
#pragma unroll
            for (int fn = 0; fn < 2; ++fn) {
                int row = wc * 32 + fn * 16 + (l & 15);
                int idx = frag_idx(row, ks, l);
                bh[fn] = *(const bf16x8*)&Bh_s[idx];
                bl[fn] = *(const bf16x8*)&Bl_s[idx];
            }
#pragma unroll
            for (int fm = 0; fm < 2; ++fm)
#pragma unroll
                for (int fn = 0; fn < 2; ++fn) {
                    acc[fm][fn] = __builtin_amdgcn_mfma_f32_16x16x32_bf16(ah[fm], bh[fn], acc[fm][fn], 0, 0, 0);
                    acc[fm][fn] = __builtin_amdgcn_mfma_f32_16x16x32_bf16(ah[fm], bl[fn], acc[fm][fn], 0, 0, 0);
                }
        }
        __syncthreads();
    }

    const float* st = style + b * 2 * CDIM;
#pragma unroll
    for (int fn = 0; fn < 2; ++fn) {
        int col = bn * 128 + wc * 32 + fn * 16 + (l & 15);
        float ga = st[col], be = st[CDIM + col];
        float pmv = 0.f;
#pragma unroll
        for (int fm = 0; fm < 2; ++fm) {
            int m0 = bm * 64 + wr * 32 + fm * 16 + (l >> 4) * 4;
#pragma unroll
            for (int r = 0; r < 4; ++r) {
                float v = lrelu(ga * acc[fm][fn][r] + be);
                size_t off = ((size_t)(b * 1024 + m0 + r)) * 256 + col;
                if (x) x[off] = v;
                if (xh) {
                    unsigned short h = bf16_hi(v);
                    xh[off] = h;
                    xl[off] = bf16_hi(v - bf16_tof(h));
                }
                pmv += abar[b * 1024 + m0 + r] * v;
            }
        }
        if (mv) atomicAdd(&mvred[wc * 32 + fn * 16 + (l & 15)], pmv);
    }
    if (mv) {
        __syncthreads();
        if (tid < 128) atomicAdd(&mv[b * 256 + bn * 128 + tid], mvred[tid]);
    }
}

// ---------------------------------------------------------------------------
// MFMA split-3 GEMM (h1 = x @ W'^T + b, transposed bf16 hi/lo output),
// 512 thr / 8 waves, PLUS style MLP at blockIdx.y == 4 (wave-per-output).
// ---------------------------------------------------------------------------
__global__ __launch_bounds__(512) void gemm_nt_mfma_kernel(
    const unsigned short* __restrict__ xh_g, const unsigned short* __restrict__ xl_g,
    const unsigned short* __restrict__ Wh, const unsigned short* __restrict__ Wl,
    const float* __restrict__ bias,
    unsigned short* __restrict__ h1t_h, unsigned short* __restrict__ h1t_l,
    const float* __restrict__ mv, const float* __restrict__ sumabar,
    const float* __restrict__ Wblk_f,
    const float* __restrict__ W1, const float* __restrict__ b1,
    const float* __restrict__ W2, const float* __restrict__ b2,
    float* __restrict__ style, float sc_c, float sc_2c)
{
    __shared__ __align__(16) unsigned short Ah_s[128 * 64];
    __shared__ __align__(16) unsigned short Al_s[128 * 64];
    __shared__ __align__(16) unsigned short Bh_s[64 * 64];
    __shared__ __align__(16) unsigned short Bl_s[64 * 64];
    const int tid = threadIdx.x;
    const int bm = blockIdx.x, bn = blockIdx.y;

    if (bn == 4) {
        if (bm >= BATCH * 4) return;
        const int bb = bm >> 2;
        const int q = bm & 3;
        const int w = tid >> 6, lane = tid & 63;
        float* m_s = (float*)Ah_s;
        float* s1_s = (float*)Bh_s;

        const float4 mvreg = *(const float4*)&mv[bb * 256 + lane * 4];
        const float sab = sumabar[bb];

        for (int g = 0; g < 4; ++g) {
            const int o0 = w * 32 + g * 8;
            float p[8];
#pragma unroll
            for (int jj = 0; jj < 8; ++jj) {
                const float4 wv = *(const float4*)&Wblk_f[(size_t)(o0 + jj) * 256 + lane * 4];
                p[jj] = dot4(wv, mvreg);
            }
#pragma unroll
            for (int off = 32; off > 0; off >>= 1)
#pragma unroll
                for (int jj = 0; jj < 8; ++jj) p[jj] += __shfl_xor(p[jj], off);
            if (lane == 0)
#pragma unroll
                for (int jj = 0; jj < 8; ++jj)
                    m_s[o0 + jj] = sc_c * p[jj] + sab * bias[o0 + jj];
        }
        __syncthreads();
        const float4 mreg = *(const float4*)&m_s[lane * 4];

        for (int g = 0; g < 8; ++g) {
            const int o0 = w * 64 + g * 8;
            float p[8];
#pragma unroll
            for (int jj = 0; jj < 8; ++jj) {
                const float4 wv = *(const float4*)&W1[(size_t)(o0 + jj) * 256 + lane * 4];
                p[jj] = dot4(wv, mreg);
            }
#pragma unroll
            for (int off = 32; off > 0; off >>= 1)
#pragma unroll
                for (int jj = 0; jj < 8; ++jj) p[jj] += __shfl_xor(p[jj], off);
            if (lane == 0)
#pragma unroll
                for (int jj = 0; jj < 8; ++jj)
                    s1_s[o0 + jj] = lrelu(sc_c * p[jj] + b1[o0 + jj]);
        }
        __syncthreads();
        const float4 sa = *(const float4*)&s1_s[lane * 4];
        const float4 sb = *(const float4*)&s1_s[256 + lane * 4];

        for (int g = 0; g < 2; ++g) {
            const int o0 = q * 128 + w * 16 + g * 8;
            float p[8];
#pragma unroll
            for (int jj = 0; jj < 8; ++jj) {
                const float4 wa = *(const float4*)&W2[(size_t)(o0 + jj) * 512 + lane * 4];
                const float4 wb = *(const float4*)&W2[(size_t)(o0 + jj) * 512 + 256 + lane * 4];
                p[jj] = dot4(wa, sa) + dot4(wb, sb);
            }
#pragma unroll
            for (int off = 32; off > 0; off >>= 1)
#pragma unroll
                for (int jj = 0; jj < 8; ++jj) p[jj] += __shfl_xor(p[jj], off);
            if (lane == 0)
#pragma unroll
                for (int jj = 0; jj < 8; ++jj)
                    style[bb * 512 + o0 + jj] = sc_2c * p[jj] + b2[o0 + jj];
        }
        return;
    }

    // ---- GEMM path (8 waves, wave-tile 64x16) ----
    const int l = tid & 63, wave = tid >> 6;
    const int wr = wave >> 2, wc = wave & 3;
    const int row0 = bm * 128;
    const int b = row0 >> 10;

    const unsigned short* Ag_h = xh_g + (size_t)row0 * 256;
    const unsigned short* Ag_l = xl_g + (size_t)row0 * 256;
    const unsigned short* Bg_h = Wh + (size_t)(bn * 64) * 256;
    const unsigned short* Bg_l = Wl + (size_t)(bn * 64) * 256;

    f32x4 acc[4];
#pragma unroll
    for (int i = 0; i < 4; ++i) acc[i] = (f32x4){0.f, 0.f, 0.f, 0.f};

    for (int kt = 0; kt < 4; ++kt) {
        stage_tile(Ag_h + kt * 64, 256, Ah_s, tid, 2, 512);
        stage_tile(Ag_l + kt * 64, 256, Al_s, tid, 2, 512);
        stage_tile(Bg_h + kt * 64, 256, Bh_s, tid, 1, 512);
        stage_tile(Bg_l + kt * 64, 256, Bl_s, tid, 1, 512);
        __syncthreads();
#pragma unroll
        for (int ks = 0; ks < 2; ++ks) {
            bf16x8 ah[4], al[4], bh, bl;
#pragma unroll
            for (int fm = 0; fm < 4; ++fm) {
                int row = wr * 64 + fm * 16 + (l & 15);
                int idx = frag_idx(row, ks, l);
                ah[fm] = *(const bf16x8*)&Ah_s[idx];
                al[fm] = *(const bf16x8*)&Al_s[idx];
            }
            {
                int row = wc * 16 + (l & 15);
                int idx = frag_idx(row, ks, l);
                bh = *(const bf16x8*)&Bh_s[idx];
                bl = *(const bf16x8*)&Bl_s[idx];
            }
#pragma unroll
            for (int fm = 0; fm < 4; ++fm) {
                acc[fm] = __builtin_amdgcn_mfma_f32_16x16x32_bf16(ah[fm], bh, acc[fm], 0, 0, 0);
                acc[fm] = __builtin_amdgcn_mfma_f32_16x16x32_bf16(ah[fm], bl, acc[fm], 0, 0, 0);
                acc[fm] = __builtin_amdgcn_mfma_f32_16x16x32_bf16(al[fm], bh, acc[fm], 0, 0, 0);
            }
        }
        __syncthreads();
    }

    {
        int col = bn * 64 + wc * 16 + (l & 15);
        float bi = bias[col];
#pragma unroll
        for (int fm = 0; fm < 4; ++fm) {
            int s0 = (row0 & 1023) + wr * 64 + fm * 16 + (l >> 4) * 4;
            float v0 = acc[fm][0] + bi;
            float v1 = acc[fm][1] + bi;
            float v2 = acc[fm][2] + bi;
            float v3 = acc[fm][3] + bi;
            ushort4 hv, lv;
            hv.x = bf16_hi(v0); lv.x = bf16_hi(v0 - bf16_tof(hv.x));
            hv.y = bf16_hi(v1); lv.y = bf16_hi(v1 - bf16_tof(hv.y));
            hv.z = bf16_hi(v2); lv.z = bf16_hi(v2 - bf16_tof(hv.z));
            hv.w = bf16_hi(v3); lv.w = bf16_hi(v3 - bf16_tof(hv.w));
            size_t off = ((size_t)(b * 256 + col)) * 1024 + s0;
            *(ushort4*)&h1t_h[off] = hv;
            *(ushort4*)&h1t_l[off] = lv;
        }
    }
}

// ---------------------------------------------------------------------------
// fp32 VALU gemm_nt (proj only) + mv + bf16 emit
// ---------------------------------------------------------------------------
#define BM 64
#define BN 64
#define BK 16
__global__ __launch_bounds__(256) void gemm_nt_kernel(
    const float* __restrict__ A, const float* __restrict__ B,
    float* __restrict__ C, int K, float alpha, const float* __restrict__ bias,
    const float* __restrict__ abar, float* __restrict__ mv,
    unsigned short* __restrict__ xh, unsigned short* __restrict__ xl)
{
    __shared__ float As[BK][BM + 4];
    __shared__ float Bs[BK][BN + 4];
    __shared__ float red[16][BN];
    const int tid = threadIdx.x;
    const int bm = blockIdx.x, bn = blockIdx.y;
    const int tx = tid & 15, ty = tid >> 4;
    const int lrow = tid >> 2;
    const int lk = (tid & 3) << 2;
    const float* Ag = A + (size_t)(bm * BM + lrow) * K + lk;
    const float* Bg = B + (size_t)(bn * BN + lrow) * K + lk;
    float acc[4][4] = {};

    for (int k0 = 0; k0 < K; k0 += BK) {
        float4 av = *(const float4*)(Ag + k0);
        float4 bv = *(const float4*)(Bg + k0);
        __syncthreads();
        As[lk + 0][lrow] = av.x; As[lk + 1][lrow] = av.y;
        As[lk + 2][lrow] = av.z; As[lk + 3][lrow] = av.w;
        Bs[lk + 0][lrow] = bv.x; Bs[lk + 1][lrow] = bv.y;
        Bs[lk + 2][lrow] = bv.z; Bs[lk + 3][lrow] = bv.w;
        __syncthreads();
#pragma unroll
        for (int kk = 0; kk < BK; ++kk) {
            const float4 a = *(const float4*)&As[kk][ty << 2];
            const float4 b = *(const float4*)&Bs[kk][tx << 2];
            float ar[4] = {a.x, a.y, a.z, a.w};
            float br[4] = {b.x, b.y, b.z, b.w};
#pragma unroll
            for (int i = 0; i < 4; ++i)
#pragma unroll
                for (int jj = 0; jj < 4; ++jj)
                    acc[i][jj] += ar[i] * br[jj];
        }
    }
    const int row = bm * BM + (ty << 2);
    const int col = bn * BN + (tx << 2);
    const int b = row >> 10;
    float bi[4] = {bias[col], bias[col + 1], bias[col + 2], bias[col + 3]};
    float o[4][4];
#pragma unroll
    for (int i = 0; i < 4; ++i) {
        float4 ov;
        ov.x = o[i][0] = alpha * acc[i][0] + bi[0];
        ov.y = o[i][1] = alpha * acc[i][1] + bi[1];
        ov.z = o[i][2] = alpha * acc[i][2] + bi[2];
        ov.w = o[i][3] = alpha * acc[i][3] + bi[3];
        *(float4*)(C + (size_t)(row + i) * CDIM + col) = ov;
#pragma unroll
        for (int jj = 0; jj < 4; ++jj) {
            size_t off = (size_t)(row + i) * CDIM + col + jj;
            unsigned short h = bf16_hi(o[i][jj]);
            xh[off] = h;
            xl[off] = bf16_hi(o[i][jj] - bf16_tof(h));
        }
    }
    {
        float p[4];
#pragma unroll
        for (int jj = 0; jj < 4; ++jj) {
            p[jj] = 0.f;
#pragma unroll
            for (int i = 0; i < 4; ++i)
                p[jj] += abar[((row + i) & 1023) + (b << 10)] * o[i][jj];
            red[ty][(tx << 2) + jj] = p[jj];
        }
        __syncthreads();
        if (tid < BN) {
            float s = 0.f;
#pragma unroll
            for (int tt = 0; tt < 16; ++tt) s += red[tt][tid];
            atomicAdd(&mv[b * CDIM + bn * BN + tid], s);
        }
    }
}

// ---------------------------------------------------------------------------
// color: writes tanh'd color table
// ---------------------------------------------------------------------------
__global__ __launch_bounds__(256) void color_kernel(
    const float* __restrict__ x, const float* __restrict__ rgb_w,
    const float* __restrict__ rgb_b, float* __restrict__ color, float sc_c)
{
    const int wave = threadIdx.x >> 6;
    const int lane = threadIdx.x & 63;
    const int r = blockIdx.x * 4 + wave;
    const float4 xv = *(const float4*)(x + (size_t)r * CDIM + lane * 4);
    float p[3];
#pragma unroll
    for (int cc = 0; cc < 3; ++cc) {
        const float4 wv = *(const float4*)(rgb_w + cc * CDIM + lane * 4);
        p[cc] = xv.x * wv.x + xv.y * wv.y + xv.z * wv.z + xv.w * wv.w;
    }
#pragma unroll
    for (int off = 32; off > 0; off >>= 1) {
#pragma unroll
        for (int cc = 0; cc < 3; ++cc) p[cc] += __shfl_down(p[cc], off);
    }
    if (lane == 0) {
#pragma unroll
        for (int cc = 0; cc < 3; ++cc)
            color[(size_t)r * 3 + cc] = tanhf(sc_c * p[cc] + rgb_b[cc]);
    }
}

// ---------------------------------------------------------------------------
// gather: 4 pixels/thread, float4 stores per plane
// ---------------------------------------------------------------------------
__global__ __launch_bounds__(256) void gather_kernel(
    const int* __restrict__ seg, const float* __restrict__ color,
    float* __restrict__ out)
{
    int idx = blockIdx.x * 256 + threadIdx.x;
    int b = idx >> 16;
    int p4 = idx & 65535;
    int4 s = ((const int4*)(seg + (size_t)b * N_PIX))[p4];
    const float* cb = color + (size_t)b * S_SEG * 3;
    float4 o0, o1, o2;
    o0.x = cb[s.x * 3 + 0]; o1.x = cb[s.x * 3 + 1]; o2.x = cb[s.x * 3 + 2];
    o0.y = cb[s.y * 3 + 0]; o1.y = cb[s.y * 3 + 1]; o2.y = cb[s.y * 3 + 2];
    o0.z = cb[s.z * 3 + 0]; o1.z = cb[s.z * 3 + 1]; o2.z = cb[s.z * 3 + 2];
    o0.w = cb[s.w * 3 + 0]; o1.w = cb[s.w * 3 + 1]; o2.w = cb[s.w * 3 + 2];
    ((float4*)(out + ((size_t)b * 3 + 0) * N_PIX))[p4] = o0;
    ((float4*)(out + ((size_t)b * 3 + 1) * N_PIX))[p4] = o1;
    ((float4*)(out + ((size_t)b * 3 + 2) * N_PIX))[p4] = o2;
}

// ---------------------------------------------------------------------------
extern "C" void kernel_launch(void* const* d_in, const int* in_sizes, int n_in,
                              void* d_out, int out_size, void* d_ws, size_t ws_size,
                              hipStream_t stream)
{
    (void)in_sizes; (void)n_in; (void)out_size; (void)ws_size;
    const float* z      = (const float*)d_in[0];
    const float* images = (const float*)d_in[1];
    const int*   seg    = (const int*)d_in[2];
    const float* A      = (const float*)d_in[3];
    const float* proj_w = (const float*)d_in[4];
    const float* proj_b = (const float*)d_in[5];
    const float* blk_w  = (const float*)d_in[6];
    const float* blk_b  = (const float*)d_in[7];
    const float* ada_w1 = (const float*)d_in[8];
    const float* ada_b1 = (const float*)d_in[9];
    const float* ada_w2 = (const float*)d_in[10];
    const float* ada_b2 = (const float*)d_in[11];
    const float* rgb_w  = (const float*)d_in[12];
    const float* rgb_b  = (const float*)d_in[13];
    float* out = (float*)d_out;

    float* ws = (float*)d_ws;
    float* mv       = ws;                   // 18432 (zeroed)
    float* sumabar  = ws + 18432;           // 16   (zeroed)
    float* abar     = ws + 18448;           // 8192
    float* style    = ws + 26640;           // 4096
    float* colr     = ws + 30736;           // 24576
    float* wpad     = ws + 55312;           // 36864
    float* xin      = ws + 92176;           // 1179648 -> 1271824
    float* x        = ws + 1271824;         // 2097152 -> 3368976
    unsigned short* xh    = (unsigned short*)(ws + 3368976);
    unsigned short* xl    = (unsigned short*)(ws + 4417552);
    unsigned short* h1t_h = (unsigned short*)(ws + 5466128);
    unsigned short* h1t_l = (unsigned short*)(ws + 6514704);
    unsigned short* Ah    = (unsigned short*)(ws + 7563280);   // 8M ushort
    unsigned short* Wh    = (unsigned short*)(ws + 15951888);
    unsigned short* Wl    = (unsigned short*)(ws + 16214032);
    float* seg_slab = ws + 16476176;        // 1048576 -> 17524752
    float* A_slab   = ws + 17524752;        // 262144  -> 17786896

    const float sc_in = (float)sqrt(2.0 / 131.0);
    const float sc_c  = (float)sqrt(2.0 / 256.0);
    const float sc_2c = (float)sqrt(2.0 / 512.0);

    (void)hipMemsetAsync(mv, 0, 18448 * sizeof(float), stream);
    prep_all_kernel<<<dim3(641), 1024, 0, stream>>>(
        images, seg, seg_slab, A, Ah, A_slab,
        blk_w, Wh, Wl, sc_c, proj_w, wpad);
    prep_xin_kernel<<<dim3(4640), 256, 0, stream>>>(
        seg_slab, A_slab, z, xin, abar, sumabar);

    gemm_nt_kernel<<<dim3(128, 4), 256, 0, stream>>>(xin, wpad, x, 144, sc_in, proj_b,
                                                     abar, mv, xh, xl);

    for (int i = 0; i < 8; ++i) {
        gemm_nt_mfma_kernel<<<dim3(64, 5), 512, 0, stream>>>(
            xh, xl, Wh + (size_t)i * 65536, Wl + (size_t)i * 65536,
            blk_b + i * CDIM, h1t_h, h1t_l,
            mv + i * 2048, sumabar, blk_w + (size_t)i * CDIM * CDIM,
            ada_w1 + (size_t)i * 512 * 256, ada_b1 + i * 512,
            ada_w2 + (size_t)i * 512 * 512, ada_b2 + i * 512,
            style, sc_c, sc_2c);
        const bool last = (i == 7);
        gemm_nn_mfma_kernel<<<dim3(256), 512, 0, stream>>>(
            Ah, h1t_h, h1t_l, style, abar,
            last ? x : nullptr,
            last ? nullptr : xh, last ? nullptr : xl,
            last ? nullptr : (mv + (i + 1) * 2048));
    }

    color_kernel<<<dim3(2048), 256, 0, stream>>>(x, rgb_w, rgb_b, colr, sc_c);
    gather_kernel<<<dim3(2048), 256, 0, stream>>>(seg, colr, out);
}

// Round 15
// 452.407 us; speedup vs baseline: 1.2249x; 1.1379x over previous
//
#include <hip/hip_runtime.h>
#include <math.h>

#define N_PIX (512*512)
#define S_SEG 1024
#define CDIM  256
#define BATCH 8

typedef __attribute__((ext_vector_type(4))) float f32x4;
typedef __attribute__((ext_vector_type(8))) short bf16x8;
typedef __fp16 half2v __attribute__((ext_vector_type(2)));
typedef __attribute__((address_space(3))) unsigned int lds_uint;

__device__ __forceinline__ float lrelu(float v) { return v > 0.f ? v : 0.2f * v; }

__device__ __forceinline__ unsigned short bf16_hi(float x) {
    union { float f; unsigned int u; } v; v.f = x;
    unsigned int r = v.u + 0x7FFFu + ((v.u >> 16) & 1u);
    return (unsigned short)(r >> 16);
}
__device__ __forceinline__ float bf16_tof(unsigned short h) {
    union { float f; unsigned int u; } v; v.u = ((unsigned int)h) << 16;
    return v.f;
}
__device__ __forceinline__ float dot4(float4 a, float4 b) {
    return a.x * b.x + a.y * b.y + a.z * b.z + a.w * b.w;
}
__device__ __forceinline__ unsigned pack_h2(float lo, float hi) {
    union { half2v h; unsigned u; } c;
    c.h = __builtin_amdgcn_cvt_pkrtz(lo, hi);
    return c.u;
}
__device__ __forceinline__ void ds_pk_add(lds_uint* p, unsigned val) {
    asm volatile("ds_pk_add_f16 %0, %1"
                 :: "v"((unsigned)(unsigned long)p), "v"(val) : "memory");
}

// ---------------------------------------------------------------------------
// MERGED prep (unchanged from R14: A -> Ah only, atomic-free flush)
// ---------------------------------------------------------------------------
__global__ __launch_bounds__(1024) void prep_all_kernel(
    const float* __restrict__ images, const int* __restrict__ seg,
    float* __restrict__ seg_slab,
    const float* __restrict__ A, unsigned short* __restrict__ Ah,
    float* __restrict__ A_slab,
    const float* __restrict__ blk_w, unsigned short* __restrict__ Wh,
    unsigned short* __restrict__ Wl, float sc_c,
    const float* __restrict__ proj_w, float* __restrict__ wpad)
{
    __shared__ unsigned int sm[4096];
    const int blk = blockIdx.x;
    const int t = threadIdx.x;

    if (blk < 256) {
        const int b = blk >> 5;
        const int chunk = blk & 31;
        for (int i = t; i < S_SEG * 2; i += 1024) sm[i] = 0u;
        __syncthreads();

        lds_uint* bl2 = (lds_uint*)sm;
        const float4* imr = (const float4*)(images + (size_t)b * 3 * N_PIX);
        const float4* img = imr + N_PIX / 4;
        const float4* imb = img + N_PIX / 4;
        const int4* sg4 = (const int4*)(seg + (size_t)b * N_PIX);
        const int base4 = chunk * (N_PIX / 32 / 4);

#pragma unroll
        for (int it = 0; it < 2; ++it) {
            int p4 = base4 + it * 1024 + t;
            int4 s = sg4[p4];
            float4 r = imr[p4];
            float4 g = img[p4];
            float4 bb = imb[p4];
            ds_pk_add(bl2 + s.x * 2 + 0, pack_h2(r.x, g.x));
            ds_pk_add(bl2 + s.x * 2 + 1, pack_h2(bb.x, 1.f));
            ds_pk_add(bl2 + s.y * 2 + 0, pack_h2(r.y, g.y));
            ds_pk_add(bl2 + s.y * 2 + 1, pack_h2(bb.y, 1.f));
            ds_pk_add(bl2 + s.z * 2 + 0, pack_h2(r.z, g.z));
            ds_pk_add(bl2 + s.z * 2 + 1, pack_h2(bb.z, 1.f));
            ds_pk_add(bl2 + s.w * 2 + 0, pack_h2(r.w, g.w));
            ds_pk_add(bl2 + s.w * 2 + 1, pack_h2(bb.w, 1.f));
        }
        __syncthreads();
        if (t < S_SEG) {
            union { unsigned u; __fp16 h[2]; } p0, p1;
            p0.u = sm[t * 2 + 0];
            p1.u = sm[t * 2 + 1];
            float4 o;
            o.x = (float)p0.h[0];
            o.y = (float)p0.h[1];
            o.z = (float)p1.h[0];
            o.w = (float)p1.h[1];
            ((float4*)seg_slab)[(size_t)blk * 1024 + t] = o;
        }
        return;
    }

    if (blk < 512) {
        const int ablk = blk - 256;
        const int b = ablk >> 5;
        const int chunk = ablk & 31;
        const int col = t & 255;
        const int rg = t >> 8;
        const size_t base4 = (((size_t)b * 1024 * 1024 + (size_t)chunk * 32 * 1024) >> 2)
                             + (size_t)rg * 8 * 256;
        const float4* Af = ((const float4*)A) + base4;
        ushort4* Ahf = ((ushort4*)Ah) + base4;
        float a0 = 0.f, a1 = 0.f, a2 = 0.f, a3 = 0.f;
#pragma unroll
        for (int r = 0; r < 8; ++r) {
            float4 v = Af[r * 256 + col];
            ushort4 h;
            h.x = bf16_hi(v.x);
            h.y = bf16_hi(v.y);
            h.z = bf16_hi(v.z);
            h.w = bf16_hi(v.w);
            Ahf[r * 256 + col] = h;
            a0 += v.x; a1 += v.y; a2 += v.z; a3 += v.w;
        }
        float4* red4 = (float4*)sm;
        float4 p; p.x = a0; p.y = a1; p.z = a2; p.w = a3;
        red4[rg * 256 + col] = p;
        __syncthreads();
        if (t < 256) {
            float4 s0 = red4[t], s1 = red4[256 + t], s2 = red4[512 + t], s3 = red4[768 + t];
            float4 o;
            o.x = s0.x + s1.x + s2.x + s3.x;
            o.y = s0.y + s1.y + s2.y + s3.y;
            o.z = s0.z + s1.z + s2.z + s3.z;
            o.w = s0.w + s1.w + s2.w + s3.w;
            ((float4*)A_slab)[(size_t)ablk * 256 + t] = o;
        }
        return;
    }

    if (blk < 640) {
        unsigned int idx = (blk - 512) * 1024 + t;
        float4 v = ((const float4*)blk_w)[idx];
        ushort4 h, l;
        float a;
        a = v.x * sc_c; h.x = bf16_hi(a); l.x = bf16_hi(a - bf16_tof(h.x));
        a = v.y * sc_c; h.y = bf16_hi(a); l.y = bf16_hi(a - bf16_tof(h.y));
        a = v.z * sc_c; h.z = bf16_hi(a); l.z = bf16_hi(a - bf16_tof(h.z));
        a = v.w * sc_c; h.w = bf16_hi(a); l.w = bf16_hi(a - bf16_tof(h.w));
        ((ushort4*)Wh)[idx] = h;
        ((ushort4*)Wl)[idx] = l;
        return;
    }

    for (int i = t; i < 256 * 144; i += 1024) {
        int n = i / 144, k = i % 144;
        wpad[i] = (k < 131) ? proj_w[n * 131 + k] : 0.f;
    }
}

// ---------------------------------------------------------------------------
// prep_xin + slab reductions (unchanged)
// ---------------------------------------------------------------------------
__global__ __launch_bounds__(256) void prep_xin_kernel(
    const float* __restrict__ seg_slab, const float* __restrict__ A_slab,
    const float* __restrict__ z, float* __restrict__ xin,
    float* __restrict__ abar, float* __restrict__ sumabar)
{
    const int t = threadIdx.x;
    if (blockIdx.x >= 4608) {
        int idx = (blockIdx.x - 4608) * 256 + t;
        int b = idx >> 10, s = idx & 1023;
        float acc = 0.f;
        const float* sl = A_slab + (size_t)(b << 5) * 1024 + s;
#pragma unroll 8
        for (int ch = 0; ch < 32; ++ch) acc += sl[ch * 1024];
        float v = acc * (1.f / 1024.f);
        abar[idx] = v;
        __shared__ float red[256];
        red[t] = v;
        __syncthreads();
        for (int off = 128; off > 0; off >>= 1) {
            if (t < off) red[t] += red[t + off];
            __syncthreads();
        }
        if (t == 0) atomicAdd(&sumabar[b], red[0]);
        return;
    }

    int idx = blockIdx.x * 256 + t;
    int r = idx / 144, c = idx % 144;
    int b = r >> 10;
    float v;
    if (c < 3) {
        int s = r & 1023;
        const float4* sl = (const float4*)seg_slab + (size_t)(b << 5) * 1024 + s;
        float cnt = 0.f, sc = 0.f;
#pragma unroll 8
        for (int ch = 0; ch < 32; ++ch) {
            float4 w = sl[ch * 1024];
            cnt += w.w;
            sc += (c == 0) ? w.x : ((c == 1) ? w.y : w.z);
        }
        v = sc / (cnt + 1e-6f);
    } else if (c < 131) {
        v = z[b * 128 + (c - 3)];
    } else {
        v = 0.f;
    }
    xin[idx] = v;
}

// ---------------------------------------------------------------------------
// staging helpers (rule #21 both-sides swizzle); T = block thread count
// ---------------------------------------------------------------------------
__device__ __forceinline__ void stage_tile(
    const unsigned short* __restrict__ g, int grow,
    unsigned short* lds, int tid, int nissue, int T)
{
    for (int i = 0; i < nissue; ++i) {
        int c = i * T + tid;
        int row = c >> 3, cin = c & 7;
        int cs = cin ^ (row & 7);
        const unsigned short* src = g + (size_t)row * grow + cs * 8;
        unsigned short* dst = lds + (size_t)(i * T + (tid & ~63)) * 8;
        __builtin_amdgcn_global_load_lds(
            (const __attribute__((address_space(1))) unsigned int*)src,
            (__attribute__((address_space(3))) unsigned int*)dst, 16, 0, 0);
    }
}

__device__ __forceinline__ int frag_idx(int row, int ks, int l)
{
    int chunk = (ks * 4 + (l >> 4)) ^ (row & 7);
    return row * 64 + chunk * 8;
}

// ---------------------------------------------------------------------------
// MFMA GEMM: x_out = lrelu(gamma*(A @ h1) + beta). A plain bf16, h1 now ALSO
// plain bf16 (h1t_l dropped: halves the dominant B-traffic + MFMA count).
// Tile 64x128, 512 thr / 8 waves, 1-D grid 256 with XCD-aware mapping.
// ---------------------------------------------------------------------------
__global__ __launch_bounds__(512) void gemm_nn_mfma_kernel(
    const unsigned short* __restrict__ Ah_g,
    const unsigned short* __restrict__ Hh_g,
    const float* __restrict__ style, const float* __restrict__ abar,
    float* __restrict__ x, unsigned short* __restrict__ xh,
    unsigned short* __restrict__ xl, float* __restrict__ mv)
{
    __shared__ __align__(16) unsigned short Ah_s[64 * 64];
    __shared__ __align__(16) unsigned short Bh_s[128 * 64];
    __shared__ float mvred[128];
    const int tid = threadIdx.x;
    const int bid = blockIdx.x;
    const int xcd = bid & 7;
    const int j = bid >> 3;
    const int pairidx = (xcd << 1) | (j >> 4);
    const int bm = j & 15;
    const int bn = pairidx & 1;
    const int b = pairidx >> 1;
    const int l = tid & 63, wave = tid >> 6;
    const int wr = wave >> 2, wc = wave & 3;
    if (mv && tid < 128) mvred[tid] = 0.f;

    const unsigned short* Ag_h = Ah_g + ((size_t)(b * 1024 + bm * 64)) * 1024;
    const unsigned short* Hg_h = Hh_g + ((size_t)(b * 256 + bn * 128)) * 1024;

    f32x4 acc[2][2];
#pragma unroll
    for (int i = 0; i < 2; ++i)
#pragma unroll
        for (int jj = 0; jj < 2; ++jj) acc[i][jj] = (f32x4){0.f, 0.f, 0.f, 0.f};

    for (int kt = 0; kt < 16; ++kt) {
        stage_tile(Ag_h + kt * 64, 1024, Ah_s, tid, 1, 512);
        stage_tile(Hg_h + kt * 64, 1024, Bh_s, tid, 2, 512);
        __syncthreads();
#pragma unroll
        for (int ks = 0; ks < 2; ++ks) {
            bf16x8 ah[2], bh[2];
#pragma unroll
            for (int fm = 0; fm < 2; ++fm) {
                int row = wr * 32 + fm * 16 + (l & 15);
                int idx = frag_idx(row, ks, l);
                ah[fm] = *(const bf16x8*)&Ah_s[idx];
            }
#pragma unroll
            for (int fn = 0; fn < 2; ++fn) {
                int row = wc * 32 + fn * 16 + (l & 15);
                int idx = frag_idx(row, ks, l);
                bh[fn] = *(const bf16x8*)&Bh_s[idx];
            }
#pragma unroll
            for (int fm = 0; fm < 2; ++fm)
#pragma unroll
                for (int fn = 0; fn < 2; ++fn)
                    acc[fm][fn] = __builtin_amdgcn_mfma_f32_16x16x32_bf16(ah[fm], bh[fn], acc[fm][fn], 0, 0, 0);
        }
        __syncthreads();
    }

    const float* st = style + b * 2 * CDIM;
#pragma unroll
    for (int fn = 0; fn < 2; ++fn) {
        int col = bn * 128 + wc * 32 + fn * 16 + (l & 15);
        float ga = st[col], be = st[CDIM + col];
        float pmv = 0.f;
#pragma unroll
        for (int fm = 0; fm < 2; ++fm) {
            int m0 = bm * 64 + wr * 32 + fm * 16 + (l >> 4) * 4;
#pragma unroll
            for (int r = 0; r < 4; ++r) {
                float v = lrelu(ga * acc[fm][fn][r] + be);
                size_t off = ((size_t)(b * 1024 + m0 + r)) * 256 + col;
                if (x) x[off] = v;
                if (xh) {
                    unsigned short h = bf16_hi(v);
                    xh[off] = h;
                    xl[off] = bf16_hi(v - bf16_tof(h));
                }
                pmv += abar[b * 1024 + m0 + r] * v;
            }
        }
        if (mv) atomicAdd(&mvred[wc * 32 + fn * 16 + (l & 15)], pmv);
    }
    if (mv) {
        __syncthreads();
        if (tid < 128) atomicAdd(&mv[b * 256 + bn * 128 + tid], mvred[tid]);
    }
}

// ---------------------------------------------------------------------------
// MFMA split-3 GEMM (h1 = x @ W'^T + b), output transposed PLAIN bf16 (h1t_h
// only). 512 thr / 8 waves, PLUS style MLP at blockIdx.y == 4.
// ---------------------------------------------------------------------------
__global__ __launch_bounds__(512) void gemm_nt_mfma_kernel(
    const unsigned short* __restrict__ xh_g, const unsigned short* __restrict__ xl_g,
    const unsigned short* __restrict__ Wh, const unsigned short* __restrict__ Wl,
    const float* __restrict__ bias,
    unsigned short* __restrict__ h1t_h,
    const float* __restrict__ mv, const float* __restrict__ sumabar,
    const float* __restrict__ Wblk_f,
    const float* __restrict__ W1, const float* __restrict__ b1,
    const float* __restrict__ W2, const float* __restrict__ b2,
    float* __restrict__ style, float sc_c, float sc_2c)
{
    __shared__ __align__(16) unsigned short Ah_s[128 * 64];
    __shared__ __align__(16) unsigned short Al_s[128 * 64];
    __shared__ __align__(16) unsigned short Bh_s[64 * 64];
    __shared__ __align__(16) unsigned short Bl_s[64 * 64];
    const int tid = threadIdx.x;
    const int bm = blockIdx.x, bn = blockIdx.y;

    if (bn == 4) {
        if (bm >= BATCH * 4) return;
        const int bb = bm >> 2;
        const int q = bm & 3;
        const int w = tid >> 6, lane = tid & 63;
        float* m_s = (float*)Ah_s;
        float* s1_s = (float*)Bh_s;

        const float4 mvreg = *(const float4*)&mv[bb * 256 + lane * 4];
        const float sab = sumabar[bb];

        for (int g = 0; g < 4; ++g) {
            const int o0 = w * 32 + g * 8;
            float p[8];
#pragma unroll
            for (int jj = 0; jj < 8; ++jj) {
                const float4 wv = *(const float4*)&Wblk_f[(size_t)(o0 + jj) * 256 + lane * 4];
                p[jj] = dot4(wv, mvreg);
            }
#pragma unroll
            for (int off = 32; off > 0; off >>= 1)
#pragma unroll
                for (int jj = 0; jj < 8; ++jj) p[jj] += __shfl_xor(p[jj], off);
            if (lane == 0)
#pragma unroll
                for (int jj = 0; jj < 8; ++jj)
                    m_s[o0 + jj] = sc_c * p[jj] + sab * bias[o0 + jj];
        }
        __syncthreads();
        const float4 mreg = *(const float4*)&m_s[lane * 4];

        for (int g = 0; g < 8; ++g) {
            const int o0 = w * 64 + g * 8;
            float p[8];
#pragma unroll
            for (int jj = 0; jj < 8; ++jj) {
                const float4 wv = *(const float4*)&W1[(size_t)(o0 + jj) * 256 + lane * 4];
                p[jj] = dot4(wv, mreg);
            }
#pragma unroll
            for (int off = 32; off > 0; off >>= 1)
#pragma unroll
                for (int jj = 0; jj < 8; ++jj) p[jj] += __shfl_xor(p[jj], off);
            if (lane == 0)
#pragma unroll
                for (int jj = 0; jj < 8; ++jj)
                    s1_s[o0 + jj] = lrelu(sc_c * p[jj] + b1[o0 + jj]);
        }
        __syncthreads();
        const float4 sa = *(const float4*)&s1_s[lane * 4];
        const float4 sb = *(const float4*)&s1_s[256 + lane * 4];

        for (int g = 0; g < 2; ++g) {
            const int o0 = q * 128 + w * 16 + g * 8;
            float p[8];
#pragma unroll
            for (int jj = 0; jj < 8; ++jj) {
                const float4 wa = *(const float4*)&W2[(size_t)(o0 + jj) * 512 + lane * 4];
                const float4 wb = *(const float4*)&W2[(size_t)(o0 + jj) * 512 + 256 + lane * 4];
                p[jj] = dot4(wa, sa) + dot4(wb, sb);
            }
#pragma unroll
            for (int off = 32; off > 0; off >>= 1)
#pragma unroll
                for (int jj = 0; jj < 8; ++jj) p[jj] += __shfl_xor(p[jj], off);
            if (lane == 0)
#pragma unroll
                for (int jj = 0; jj < 8; ++jj)
                    style[bb * 512 + o0 + jj] = sc_2c * p[jj] + b2[o0 + jj];
        }
        return;
    }

    // ---- GEMM path (8 waves, wave-tile 64x16) ----
    const int l = tid & 63, wave = tid >> 6;
    const int wr = wave >> 2, wc = wave & 3;
    const int row0 = bm * 128;
    const int b = row0 >> 10;

    const unsigned short* Ag_h = xh_g + (size_t)row0 * 256;
    const unsigned short* Ag_l = xl_g + (size_t)row0 * 256;
    const unsigned short* Bg_h = Wh + (size_t)(bn * 64) * 256;
    const unsigned short* Bg_l = Wl + (size_t)(bn * 64) * 256;

    f32x4 acc[4];
#pragma unroll
    for (int i = 0; i < 4; ++i) acc[i] = (f32x4){0.f, 0.f, 0.f, 0.f};

    for (int kt = 0; kt < 4; ++kt) {
        stage_tile(Ag_h + kt * 64, 256, Ah_s, tid, 2, 512);
        stage_tile(Ag_l + kt * 64, 256, Al_s, tid, 2, 512);
        stage_tile(Bg_h + kt * 64, 256, Bh_s, tid, 1, 512);
        stage_tile(Bg_l + kt * 64, 256, Bl_s, tid, 1, 512);
        __syncthreads();
#pragma unroll
        for (int ks = 0; ks < 2; ++ks) {
            bf16x8 ah[4], al[4], bh, bl;
#pragma unroll
            for (int fm = 0; fm < 4; ++fm) {
                int row = wr * 64 + fm * 16 + (l & 15);
                int idx = frag_idx(row, ks, l);
                ah[fm] = *(const bf16x8*)&Ah_s[idx];
                al[fm] = *(const bf16x8*)&Al_s[idx];
            }
            {
                int row = wc * 16 + (l & 15);
                int idx = frag_idx(row, ks, l);
                bh = *(const bf16x8*)&Bh_s[idx];
                bl = *(const bf16x8*)&Bl_s[idx];
            }
#pragma unroll
            for (int fm = 0; fm < 4; ++fm) {
                acc[fm] = __builtin_amdgcn_mfma_f32_16x16x32_bf16(ah[fm], bh, acc[fm], 0, 0, 0);
                acc[fm] = __builtin_amdgcn_mfma_f32_16x16x32_bf16(ah[fm], bl, acc[fm], 0, 0, 0);
                acc[fm] = __builtin_amdgcn_mfma_f32_16x16x32_bf16(al[fm], bh, acc[fm], 0, 0, 0);
            }
        }
        __syncthreads();
    }

    {
        int col = bn * 64 + wc * 16 + (l & 15);
        float bi = bias[col];
#pragma unroll
        for (int fm = 0; fm < 4; ++fm) {
            int s0 = (row0 & 1023) + wr * 64 + fm * 16 + (l >> 4) * 4;
            ushort4 hv;
            hv.x = bf16_hi(acc[fm][0] + bi);
            hv.y = bf16_hi(acc[fm][1] + bi);
            hv.z = bf16_hi(acc[fm][2] + bi);
            hv.w = bf16_hi(acc[fm][3] + bi);
            size_t off = ((size_t)(b * 256 + col)) * 1024 + s0;
            *(ushort4*)&h1t_h[off] = hv;
        }
    }
}

// ---------------------------------------------------------------------------
// fp32 VALU gemm_nt (proj only) + mv + bf16 emit (unchanged)
// ---------------------------------------------------------------------------
#define BM 64
#define BN 64
#define BK 16
__global__ __launch_bounds__(256) void gemm_nt_kernel(
    const float* __restrict__ A, const float* __restrict__ B,
    float* __restrict__ C, int K, float alpha, const float* __restrict__ bias,
    const float* __restrict__ abar, float* __restrict__ mv,
    unsigned short* __restrict__ xh, unsigned short* __restrict__ xl)
{
    __shared__ float As[BK][BM + 4];
    __shared__ float Bs[BK][BN + 4];
    __shared__ float red[16][BN];
    const int tid = threadIdx.x;
    const int bm = blockIdx.x, bn = blockIdx.y;
    const int tx = tid & 15, ty = tid >> 4;
    const int lrow = tid >> 2;
    const int lk = (tid & 3) << 2;
    const float* Ag = A + (size_t)(bm * BM + lrow) * K + lk;
    const float* Bg = B + (size_t)(bn * BN + lrow) * K + lk;
    float acc[4][4] = {};

    for (int k0 = 0; k0 < K; k0 += BK) {
        float4 av = *(const float4*)(Ag + k0);
        float4 bv = *(const float4*)(Bg + k0);
        __syncthreads();
        As[lk + 0][lrow] = av.x; As[lk + 1][lrow] = av.y;
        As[lk + 2][lrow] = av.z; As[lk + 3][lrow] = av.w;
        Bs[lk + 0][lrow] = bv.x; Bs[lk + 1][lrow] = bv.y;
        Bs[lk + 2][lrow] = bv.z; Bs[lk + 3][lrow] = bv.w;
        __syncthreads();
#pragma unroll
        for (int kk = 0; kk < BK; ++kk) {
            const float4 a = *(const float4*)&As[kk][ty << 2];
            const float4 b = *(const float4*)&Bs[kk][tx << 2];
            float ar[4] = {a.x, a.y, a.z, a.w};
            float br[4] = {b.x, b.y, b.z, b.w};
#pragma unroll
            for (int i = 0; i < 4; ++i)
#pragma unroll
                for (int jj = 0; jj < 4; ++jj)
                    acc[i][jj] += ar[i] * br[jj];
        }
    }
    const int row = bm * BM + (ty << 2);
    const int col = bn * BN + (tx << 2);
    const int b = row >> 10;
    float bi[4] = {bias[col], bias[col + 1], bias[col + 2], bias[col + 3]};
    float o[4][4];
#pragma unroll
    for (int i = 0; i < 4; ++i) {
        float4 ov;
        ov.x = o[i][0] = alpha * acc[i][0] + bi[0];
        ov.y = o[i][1] = alpha * acc[i][1] + bi[1];
        ov.z = o[i][2] = alpha * acc[i][2] + bi[2];
        ov.w = o[i][3] = alpha * acc[i][3] + bi[3];
        *(float4*)(C + (size_t)(row + i) * CDIM + col) = ov;
#pragma unroll
        for (int jj = 0; jj < 4; ++jj) {
            size_t off = (size_t)(row + i) * CDIM + col + jj;
            unsigned short h = bf16_hi(o[i][jj]);
            xh[off] = h;
            xl[off] = bf16_hi(o[i][jj] - bf16_tof(h));
        }
    }
    {
        float p[4];
#pragma unroll
        for (int jj = 0; jj < 4; ++jj) {
            p[jj] = 0.f;
#pragma unroll
            for (int i = 0; i < 4; ++i)
                p[jj] += abar[((row + i) & 1023) + (b << 10)] * o[i][jj];
            red[ty][(tx << 2) + jj] = p[jj];
        }
        __syncthreads();
        if (tid < BN) {
            float s = 0.f;
#pragma unroll
            for (int tt = 0; tt < 16; ++tt) s += red[tt][tid];
            atomicAdd(&mv[b * CDIM + bn * BN + tid], s);
        }
    }
}

// ---------------------------------------------------------------------------
// color: writes tanh'd color table
// ---------------------------------------------------------------------------
__global__ __launch_bounds__(256) void color_kernel(
    const float* __restrict__ x, const float* __restrict__ rgb_w,
    const float* __restrict__ rgb_b, float* __restrict__ color, float sc_c)
{
    const int wave = threadIdx.x >> 6;
    const int lane = threadIdx.x & 63;
    const int r = blockIdx.x * 4 + wave;
    const float4 xv = *(const float4*)(x + (size_t)r * CDIM + lane * 4);
    float p[3];
#pragma unroll
    for (int cc = 0; cc < 3; ++cc) {
        const float4 wv = *(const float4*)(rgb_w + cc * CDIM + lane * 4);
        p[cc] = xv.x * wv.x + xv.y * wv.y + xv.z * wv.z + xv.w * wv.w;
    }
#pragma unroll
    for (int off = 32; off > 0; off >>= 1) {
#pragma unroll
        for (int cc = 0; cc < 3; ++cc) p[cc] += __shfl_down(p[cc], off);
    }
    if (lane == 0) {
#pragma unroll
        for (int cc = 0; cc < 3; ++cc)
            color[(size_t)r * 3 + cc] = tanhf(sc_c * p[cc] + rgb_b[cc]);
    }
}

// ---------------------------------------------------------------------------
// gather: 4 pixels/thread, float4 stores per plane
// ---------------------------------------------------------------------------
__global__ __launch_bounds__(256) void gather_kernel(
    const int* __restrict__ seg, const float* __restrict__ color,
    float* __restrict__ out)
{
    int idx = blockIdx.x * 256 + threadIdx.x;
    int b = idx >> 16;
    int p4 = idx & 65535;
    int4 s = ((const int4*)(seg + (size_t)b * N_PIX))[p4];
    const float* cb = color + (size_t)b * S_SEG * 3;
    float4 o0, o1, o2;
    o0.x = cb[s.x * 3 + 0]; o1.x = cb[s.x * 3 + 1]; o2.x = cb[s.x * 3 + 2];
    o0.y = cb[s.y * 3 + 0]; o1.y = cb[s.y * 3 + 1]; o2.y = cb[s.y * 3 + 2];
    o0.z = cb[s.z * 3 + 0]; o1.z = cb[s.z * 3 + 1]; o2.z = cb[s.z * 3 + 2];
    o0.w = cb[s.w * 3 + 0]; o1.w = cb[s.w * 3 + 1]; o2.w = cb[s.w * 3 + 2];
    ((float4*)(out + ((size_t)b * 3 + 0) * N_PIX))[p4] = o0;
    ((float4*)(out + ((size_t)b * 3 + 1) * N_PIX))[p4] = o1;
    ((float4*)(out + ((size_t)b * 3 + 2) * N_PIX))[p4] = o2;
}

// ---------------------------------------------------------------------------
extern "C" void kernel_launch(void* const* d_in, const int* in_sizes, int n_in,
                              void* d_out, int out_size, void* d_ws, size_t ws_size,
                              hipStream_t stream)
{
    (void)in_sizes; (void)n_in; (void)out_size; (void)ws_size;
    const float* z      = (const float*)d_in[0];
    const float* images = (const float*)d_in[1];
    const int*   seg    = (const int*)d_in[2];
    const float* A      = (const float*)d_in[3];
    const float* proj_w = (const float*)d_in[4];
    const float* proj_b = (const float*)d_in[5];
    const float* blk_w  = (const float*)d_in[6];
    const float* blk_b  = (const float*)d_in[7];
    const float* ada_w1 = (const float*)d_in[8];
    const float* ada_b1 = (const float*)d_in[9];
    const float* ada_w2 = (const float*)d_in[10];
    const float* ada_b2 = (const float*)d_in[11];
    const float* rgb_w  = (const float*)d_in[12];
    const float* rgb_b  = (const float*)d_in[13];
    float* out = (float*)d_out;

    float* ws = (float*)d_ws;
    float* mv       = ws;                   // 18432 (zeroed)
    float* sumabar  = ws + 18432;           // 16   (zeroed)
    float* abar     = ws + 18448;           // 8192
    float* style    = ws + 26640;           // 4096
    float* colr     = ws + 30736;           // 24576
    float* wpad     = ws + 55312;           // 36864
    float* xin      = ws + 92176;           // 1179648 -> 1271824
    float* x        = ws + 1271824;         // 2097152 -> 3368976
    unsigned short* xh    = (unsigned short*)(ws + 3368976);
    unsigned short* xl    = (unsigned short*)(ws + 4417552);
    unsigned short* h1t_h = (unsigned short*)(ws + 5466128);
    unsigned short* Ah    = (unsigned short*)(ws + 7563280);   // 8M ushort
    unsigned short* Wh    = (unsigned short*)(ws + 15951888);
    unsigned short* Wl    = (unsigned short*)(ws + 16214032);
    float* seg_slab = ws + 16476176;        // 1048576 -> 17524752
    float* A_slab   = ws + 17524752;        // 262144  -> 17786896

    const float sc_in = (float)sqrt(2.0 / 131.0);
    const float sc_c  = (float)sqrt(2.0 / 256.0);
    const float sc_2c = (float)sqrt(2.0 / 512.0);

    (void)hipMemsetAsync(mv, 0, 18448 * sizeof(float), stream);
    prep_all_kernel<<<dim3(641), 1024, 0, stream>>>(
        images, seg, seg_slab, A, Ah, A_slab,
        blk_w, Wh, Wl, sc_c, proj_w, wpad);
    prep_xin_kernel<<<dim3(4640), 256, 0, stream>>>(
        seg_slab, A_slab, z, xin, abar, sumabar);

    gemm_nt_kernel<<<dim3(128, 4), 256, 0, stream>>>(xin, wpad, x, 144, sc_in, proj_b,
                                                     abar, mv, xh, xl);

    for (int i = 0; i < 8; ++i) {
        gemm_nt_mfma_kernel<<<dim3(64, 5), 512, 0, stream>>>(
            xh, xl, Wh + (size_t)i * 65536, Wl + (size_t)i * 65536,
            blk_b + i * CDIM, h1t_h,
            mv + i * 2048, sumabar, blk_w + (size_t)i * CDIM * CDIM,
            ada_w1 + (size_t)i * 512 * 256, ada_b1 + i * 512,
            ada_w2 + (size_t)i * 512 * 512, ada_b2 + i * 512,
            style, sc_c, sc_2c);
        const bool last = (i == 7);
        gemm_nn_mfma_kernel<<<dim3(256), 512, 0, stream>>>(
            Ah, h1t_h, style, abar,
            last ? x : nullptr,
            last ? nullptr : xh, last ? nullptr : xl,
            last ? nullptr : (mv + (i + 1) * 2048));
    }

    color_kernel<<<dim3(2048), 256, 0, stream>>>(x, rgb_w, rgb_b, colr, sc_c);
    gather_kernel<<<dim3(2048), 256, 0, stream>>>(seg, colr, out);
}

// Round 16
// 443.392 us; speedup vs baseline: 1.2498x; 1.0203x over previous
//
#include <hip/hip_runtime.h>
#include <math.h>

#define N_PIX (512*512)
#define S_SEG 1024
#define CDIM  256
#define BATCH 8

typedef __attribute__((ext_vector_type(4))) float f32x4;
typedef __attribute__((ext_vector_type(8))) short bf16x8;
typedef __fp16 half2v __attribute__((ext_vector_type(2)));
typedef __attribute__((address_space(3))) unsigned int lds_uint;

__device__ __forceinline__ float lrelu(float v) { return v > 0.f ? v : 0.2f * v; }

__device__ __forceinline__ unsigned short bf16_hi(float x) {
    union { float f; unsigned int u; } v; v.f = x;
    unsigned int r = v.u + 0x7FFFu + ((v.u >> 16) & 1u);
    return (unsigned short)(r >> 16);
}
__device__ __forceinline__ float bf16_tof(unsigned short h) {
    union { float f; unsigned int u; } v; v.u = ((unsigned int)h) << 16;
    return v.f;
}
__device__ __forceinline__ float dot4(float4 a, float4 b) {
    return a.x * b.x + a.y * b.y + a.z * b.z + a.w * b.w;
}
__device__ __forceinline__ unsigned pack_h2(float lo, float hi) {
    union { half2v h; unsigned u; } c;
    c.h = __builtin_amdgcn_cvt_pkrtz(lo, hi);
    return c.u;
}
__device__ __forceinline__ void ds_pk_add(lds_uint* p, unsigned val) {
    asm volatile("ds_pk_add_f16 %0, %1"
                 :: "v"((unsigned)(unsigned long)p), "v"(val) : "memory");
}

// ---------------------------------------------------------------------------
// MERGED prep (unchanged from R15)
// ---------------------------------------------------------------------------
__global__ __launch_bounds__(1024) void prep_all_kernel(
    const float* __restrict__ images, const int* __restrict__ seg,
    float* __restrict__ seg_slab,
    const float* __restrict__ A, unsigned short* __restrict__ Ah,
    float* __restrict__ A_slab,
    const float* __restrict__ blk_w, unsigned short* __restrict__ Wh,
    unsigned short* __restrict__ Wl, float sc_c,
    const float* __restrict__ proj_w, float* __restrict__ wpad)
{
    __shared__ unsigned int sm[4096];
    const int blk = blockIdx.x;
    const int t = threadIdx.x;

    if (blk < 256) {
        const int b = blk >> 5;
        const int chunk = blk & 31;
        for (int i = t; i < S_SEG * 2; i += 1024) sm[i] = 0u;
        __syncthreads();

        lds_uint* bl2 = (lds_uint*)sm;
        const float4* imr = (const float4*)(images + (size_t)b * 3 * N_PIX);
        const float4* img = imr + N_PIX / 4;
        const float4* imb = img + N_PIX / 4;
        const int4* sg4 = (const int4*)(seg + (size_t)b * N_PIX);
        const int base4 = chunk * (N_PIX / 32 / 4);

#pragma unroll
        for (int it = 0; it < 2; ++it) {
            int p4 = base4 + it * 1024 + t;
            int4 s = sg4[p4];
            float4 r = imr[p4];
            float4 g = img[p4];
            float4 bb = imb[p4];
            ds_pk_add(bl2 + s.x * 2 + 0, pack_h2(r.x, g.x));
            ds_pk_add(bl2 + s.x * 2 + 1, pack_h2(bb.x, 1.f));
            ds_pk_add(bl2 + s.y * 2 + 0, pack_h2(r.y, g.y));
            ds_pk_add(bl2 + s.y * 2 + 1, pack_h2(bb.y, 1.f));
            ds_pk_add(bl2 + s.z * 2 + 0, pack_h2(r.z, g.z));
            ds_pk_add(bl2 + s.z * 2 + 1, pack_h2(bb.z, 1.f));
            ds_pk_add(bl2 + s.w * 2 + 0, pack_h2(r.w, g.w));
            ds_pk_add(bl2 + s.w * 2 + 1, pack_h2(bb.w, 1.f));
        }
        __syncthreads();
        if (t < S_SEG) {
            union { unsigned u; __fp16 h[2]; } p0, p1;
            p0.u = sm[t * 2 + 0];
            p1.u = sm[t * 2 + 1];
            float4 o;
            o.x = (float)p0.h[0];
            o.y = (float)p0.h[1];
            o.z = (float)p1.h[0];
            o.w = (float)p1.h[1];
            ((float4*)seg_slab)[(size_t)blk * 1024 + t] = o;
        }
        return;
    }

    if (blk < 512) {
        const int ablk = blk - 256;
        const int b = ablk >> 5;
        const int chunk = ablk & 31;
        const int col = t & 255;
        const int rg = t >> 8;
        const size_t base4 = (((size_t)b * 1024 * 1024 + (size_t)chunk * 32 * 1024) >> 2)
                             + (size_t)rg * 8 * 256;
        const float4* Af = ((const float4*)A) + base4;
        ushort4* Ahf = ((ushort4*)Ah) + base4;
        float a0 = 0.f, a1 = 0.f, a2 = 0.f, a3 = 0.f;
#pragma unroll
        for (int r = 0; r < 8; ++r) {
            float4 v = Af[r * 256 + col];
            ushort4 h;
            h.x = bf16_hi(v.x);
            h.y = bf16_hi(v.y);
            h.z = bf16_hi(v.z);
            h.w = bf16_hi(v.w);
            Ahf[r * 256 + col] = h;
            a0 += v.x; a1 += v.y; a2 += v.z; a3 += v.w;
        }
        float4* red4 = (float4*)sm;
        float4 p; p.x = a0; p.y = a1; p.z = a2; p.w = a3;
        red4[rg * 256 + col] = p;
        __syncthreads();
        if (t < 256) {
            float4 s0 = red4[t], s1 = red4[256 + t], s2 = red4[512 + t], s3 = red4[768 + t];
            float4 o;
            o.x = s0.x + s1.x + s2.x + s3.x;
            o.y = s0.y + s1.y + s2.y + s3.y;
            o.z = s0.z + s1.z + s2.z + s3.z;
            o.w = s0.w + s1.w + s2.w + s3.w;
            ((float4*)A_slab)[(size_t)ablk * 256 + t] = o;
        }
        return;
    }

    if (blk < 640) {
        unsigned int idx = (blk - 512) * 1024 + t;
        float4 v = ((const float4*)blk_w)[idx];
        ushort4 h, l;
        float a;
        a = v.x * sc_c; h.x = bf16_hi(a); l.x = bf16_hi(a - bf16_tof(h.x));
        a = v.y * sc_c; h.y = bf16_hi(a); l.y = bf16_hi(a - bf16_tof(h.y));
        a = v.z * sc_c; h.z = bf16_hi(a); l.z = bf16_hi(a - bf16_tof(h.z));
        a = v.w * sc_c; h.w = bf16_hi(a); l.w = bf16_hi(a - bf16_tof(h.w));
        ((ushort4*)Wh)[idx] = h;
        ((ushort4*)Wl)[idx] = l;
        return;
    }

    for (int i = t; i < 256 * 144; i += 1024) {
        int n = i / 144, k = i % 144;
        wpad[i] = (k < 131) ? proj_w[n * 131 + k] : 0.f;
    }
}

// ---------------------------------------------------------------------------
// prep_xin + slab reductions (unchanged)
// ---------------------------------------------------------------------------
__global__ __launch_bounds__(256) void prep_xin_kernel(
    const float* __restrict__ seg_slab, const float* __restrict__ A_slab,
    const float* __restrict__ z, float* __restrict__ xin,
    float* __restrict__ abar, float* __restrict__ sumabar)
{
    const int t = threadIdx.x;
    if (blockIdx.x >= 4608) {
        int idx = (blockIdx.x - 4608) * 256 + t;
        int b = idx >> 10, s = idx & 1023;
        float acc = 0.f;
        const float* sl = A_slab + (size_t)(b << 5) * 1024 + s;
#pragma unroll 8
        for (int ch = 0; ch < 32; ++ch) acc += sl[ch * 1024];
        float v = acc * (1.f / 1024.f);
        abar[idx] = v;
        __shared__ float red[256];
        red[t] = v;
        __syncthreads();
        for (int off = 128; off > 0; off >>= 1) {
            if (t < off) red[t] += red[t + off];
            __syncthreads();
        }
        if (t == 0) atomicAdd(&sumabar[b], red[0]);
        return;
    }

    int idx = blockIdx.x * 256 + t;
    int r = idx / 144, c = idx % 144;
    int b = r >> 10;
    float v;
    if (c < 3) {
        int s = r & 1023;
        const float4* sl = (const float4*)seg_slab + (size_t)(b << 5) * 1024 + s;
        float cnt = 0.f, sc = 0.f;
#pragma unroll 8
        for (int ch = 0; ch < 32; ++ch) {
            float4 w = sl[ch * 1024];
            cnt += w.w;
            sc += (c == 0) ? w.x : ((c == 1) ? w.y : w.z);
        }
        v = sc / (cnt + 1e-6f);
    } else if (c < 131) {
        v = z[b * 128 + (c - 3)];
    } else {
        v = 0.f;
    }
    xin[idx] = v;
}

// ---------------------------------------------------------------------------
// staging helpers (rule #21 both-sides swizzle); T = block thread count
// ---------------------------------------------------------------------------
__device__ __forceinline__ void stage_tile(
    const unsigned short* __restrict__ g, int grow,
    unsigned short* lds, int tid, int nissue, int T)
{
    for (int i = 0; i < nissue; ++i) {
        int c = i * T + tid;
        int row = c >> 3, cin = c & 7;
        int cs = cin ^ (row & 7);
        const unsigned short* src = g + (size_t)row * grow + cs * 8;
        unsigned short* dst = lds + (size_t)(i * T + (tid & ~63)) * 8;
        __builtin_amdgcn_global_load_lds(
            (const __attribute__((address_space(1))) unsigned int*)src,
            (__attribute__((address_space(3))) unsigned int*)dst, 16, 0, 0);
    }
}

__device__ __forceinline__ int frag_idx(int row, int ks, int l)
{
    int chunk = (ks * 4 + (l >> 4)) ^ (row & 7);
    return row * 64 + chunk * 8;
}

// ---------------------------------------------------------------------------
// MFMA GEMM: x_out = lrelu(gamma*(A @ h1) + beta). A, h1, x all plain bf16.
// Tile 64x128, 512 thr / 8 waves, 1-D grid 256 with XCD-aware mapping.
// ---------------------------------------------------------------------------
__global__ __launch_bounds__(512) void gemm_nn_mfma_kernel(
    const unsigned short* __restrict__ Ah_g,
    const unsigned short* __restrict__ Hh_g,
    const float* __restrict__ style, const float* __restrict__ abar,
    float* __restrict__ x, unsigned short* __restrict__ xh,
    float* __restrict__ mv)
{
    __shared__ __align__(16) unsigned short Ah_s[64 * 64];
    __shared__ __align__(16) unsigned short Bh_s[128 * 64];
    __shared__ float mvred[128];
    const int tid = threadIdx.x;
    const int bid = blockIdx.x;
    const int xcd = bid & 7;
    const int j = bid >> 3;
    const int pairidx = (xcd << 1) | (j >> 4);
    const int bm = j & 15;
    const int bn = pairidx & 1;
    const int b = pairidx >> 1;
    const int l = tid & 63, wave = tid >> 6;
    const int wr = wave >> 2, wc = wave & 3;
    if (mv && tid < 128) mvred[tid] = 0.f;

    const unsigned short* Ag_h = Ah_g + ((size_t)(b * 1024 + bm * 64)) * 1024;
    const unsigned short* Hg_h = Hh_g + ((size_t)(b * 256 + bn * 128)) * 1024;

    f32x4 acc[2][2];
#pragma unroll
    for (int i = 0; i < 2; ++i)
#pragma unroll
        for (int jj = 0; jj < 2; ++jj) acc[i][jj] = (f32x4){0.f, 0.f, 0.f, 0.f};

    for (int kt = 0; kt < 16; ++kt) {
        stage_tile(Ag_h + kt * 64, 1024, Ah_s, tid, 1, 512);
        stage_tile(Hg_h + kt * 64, 1024, Bh_s, tid, 2, 512);
        __syncthreads();
#pragma unroll
        for (int ks = 0; ks < 2; ++ks) {
            bf16x8 ah[2], bh[2];
#pragma unroll
            for (int fm = 0; fm < 2; ++fm) {
                int row = wr * 32 + fm * 16 + (l & 15);
                int idx = frag_idx(row, ks, l);
                ah[fm] = *(const bf16x8*)&Ah_s[idx];
            }
#pragma unroll
            for (int fn = 0; fn < 2; ++fn) {
                int row = wc * 32 + fn * 16 + (l & 15);
                int idx = frag_idx(row, ks, l);
                bh[fn] = *(const bf16x8*)&Bh_s[idx];
            }
#pragma unroll
            for (int fm = 0; fm < 2; ++fm)
#pragma unroll
                for (int fn = 0; fn < 2; ++fn)
                    acc[fm][fn] = __builtin_amdgcn_mfma_f32_16x16x32_bf16(ah[fm], bh[fn], acc[fm][fn], 0, 0, 0);
        }
        __syncthreads();
    }

    const float* st = style + b * 2 * CDIM;
#pragma unroll
    for (int fn = 0; fn < 2; ++fn) {
        int col = bn * 128 + wc * 32 + fn * 16 + (l & 15);
        float ga = st[col], be = st[CDIM + col];
        float pmv = 0.f;
#pragma unroll
        for (int fm = 0; fm < 2; ++fm) {
            int m0 = bm * 64 + wr * 32 + fm * 16 + (l >> 4) * 4;
#pragma unroll
            for (int r = 0; r < 4; ++r) {
                float v = lrelu(ga * acc[fm][fn][r] + be);
                size_t off = ((size_t)(b * 1024 + m0 + r)) * 256 + col;
                if (x) x[off] = v;
                if (xh) xh[off] = bf16_hi(v);
                pmv += abar[b * 1024 + m0 + r] * v;
            }
        }
        if (mv) atomicAdd(&mvred[wc * 32 + fn * 16 + (l & 15)], pmv);
    }
    if (mv) {
        __syncthreads();
        if (tid < 128) atomicAdd(&mv[b * 256 + bn * 128 + tid], mvred[tid]);
    }
}

// ---------------------------------------------------------------------------
// MFMA GEMM (h1 = x @ W'^T + b): x plain bf16, W split hi/lo (2 MFMA per
// fragment). Output transposed plain bf16. 512 thr / 8 waves, PLUS style
// MLP at blockIdx.y == 4.
// ---------------------------------------------------------------------------
__global__ __launch_bounds__(512) void gemm_nt_mfma_kernel(
    const unsigned short* __restrict__ xh_g,
    const unsigned short* __restrict__ Wh, const unsigned short* __restrict__ Wl,
    const float* __restrict__ bias,
    unsigned short* __restrict__ h1t_h,
    const float* __restrict__ mv, const float* __restrict__ sumabar,
    const float* __restrict__ Wblk_f,
    const float* __restrict__ W1, const float* __restrict__ b1,
    const float* __restrict__ W2, const float* __restrict__ b2,
    float* __restrict__ style, float sc_c, float sc_2c)
{
    __shared__ __align__(16) unsigned short Ah_s[128 * 64];
    __shared__ __align__(16) unsigned short Bh_s[64 * 64];
    __shared__ __align__(16) unsigned short Bl_s[64 * 64];
    const int tid = threadIdx.x;
    const int bm = blockIdx.x, bn = blockIdx.y;

    if (bn == 4) {
        if (bm >= BATCH * 4) return;
        const int bb = bm >> 2;
        const int q = bm & 3;
        const int w = tid >> 6, lane = tid & 63;
        float* m_s = (float*)Ah_s;
        float* s1_s = (float*)Bh_s;

        const float4 mvreg = *(const float4*)&mv[bb * 256 + lane * 4];
        const float sab = sumabar[bb];

        for (int g = 0; g < 4; ++g) {
            const int o0 = w * 32 + g * 8;
            float p[8];
#pragma unroll
            for (int jj = 0; jj < 8; ++jj) {
                const float4 wv = *(const float4*)&Wblk_f[(size_t)(o0 + jj) * 256 + lane * 4];
                p[jj] = dot4(wv, mvreg);
            }
#pragma unroll
            for (int off = 32; off > 0; off >>= 1)
#pragma unroll
                for (int jj = 0; jj < 8; ++jj) p[jj] += __shfl_xor(p[jj], off);
            if (lane == 0)
#pragma unroll
                for (int jj = 0; jj < 8; ++jj)
                    m_s[o0 + jj] = sc_c * p[jj] + sab * bias[o0 + jj];
        }
        __syncthreads();
        const float4 mreg = *(const float4*)&m_s[lane * 4];

        for (int g = 0; g < 8; ++g) {
            const int o0 = w * 64 + g * 8;
            float p[8];
#pragma unroll
            for (int jj = 0; jj < 8; ++jj) {
                const float4 wv = *(const float4*)&W1[(size_t)(o0 + jj) * 256 + lane * 4];
                p[jj] = dot4(wv, mreg);
            }
#pragma unroll
            for (int off = 32; off > 0; off >>= 1)
#pragma unroll
                for (int jj = 0; jj < 8; ++jj) p[jj] += __shfl_xor(p[jj], off);
            if (lane == 0)
#pragma unroll
                for (int jj = 0; jj < 8; ++jj)
                    s1_s[o0 + jj] = lrelu(sc_c * p[jj] + b1[o0 + jj]);
        }
        __syncthreads();
        const float4 sa = *(const float4*)&s1_s[lane * 4];
        const float4 sb = *(const float4*)&s1_s[256 + lane * 4];

        for (int g = 0; g < 2; ++g) {
            const int o0 = q * 128 + w * 16 + g * 8;
            float p[8];
#pragma unroll
            for (int jj = 0; jj < 8; ++jj) {
                const float4 wa = *(const float4*)&W2[(size_t)(o0 + jj) * 512 + lane * 4];
                const float4 wb = *(const float4*)&W2[(size_t)(o0 + jj) * 512 + 256 + lane * 4];
                p[jj] = dot4(wa, sa) + dot4(wb, sb);
            }
#pragma unroll
            for (int off = 32; off > 0; off >>= 1)
#pragma unroll
                for (int jj = 0; jj < 8; ++jj) p[jj] += __shfl_xor(p[jj], off);
            if (lane == 0)
#pragma unroll
                for (int jj = 0; jj < 8; ++jj)
                    style[bb * 512 + o0 + jj] = sc_2c * p[jj] + b2[o0 + jj];
        }
        return;
    }

    // ---- GEMM path (8 waves, wave-tile 64x16) ----
    const int l = tid & 63, wave = tid >> 6;
    const int wr = wave >> 2, wc = wave & 3;
    const int row0 = bm * 128;
    const int b = row0 >> 10;

    const unsigned short* Ag_h = xh_g + (size_t)row0 * 256;
    const unsigned short* Bg_h = Wh + (size_t)(bn * 64) * 256;
    const unsigned short* Bg_l = Wl + (size_t)(bn * 64) * 256;

    f32x4 acc[4];
#pragma unroll
    for (int i = 0; i < 4; ++i) acc[i] = (f32x4){0.f, 0.f, 0.f, 0.f};

    for (int kt = 0; kt < 4; ++kt) {
        stage_tile(Ag_h + kt * 64, 256, Ah_s, tid, 2, 512);
        stage_tile(Bg_h + kt * 64, 256, Bh_s, tid, 1, 512);
        stage_tile(Bg_l + kt * 64, 256, Bl_s, tid, 1, 512);
        __syncthreads();
#pragma unroll
        for (int ks = 0; ks < 2; ++ks) {
            bf16x8 ah[4], bh, bl;
#pragma unroll
            for (int fm = 0; fm < 4; ++fm) {
                int row = wr * 64 + fm * 16 + (l & 15);
                int idx = frag_idx(row, ks, l);
                ah[fm] = *(const bf16x8*)&Ah_s[idx];
            }
            {
                int row = wc * 16 + (l & 15);
                int idx = frag_idx(row, ks, l);
                bh = *(const bf16x8*)&Bh_s[idx];
                bl = *(const bf16x8*)&Bl_s[idx];
            }
#pragma unroll
            for (int fm = 0; fm < 4; ++fm) {
                acc[fm] = __builtin_amdgcn_mfma_f32_16x16x32_bf16(ah[fm], bh, acc[fm], 0, 0, 0);
                acc[fm] = __builtin_amdgcn_mfma_f32_16x16x32_bf16(ah[fm], bl, acc[fm], 0, 0, 0);
            }
        }
        __syncthreads();
    }

    {
        int col = bn * 64 + wc * 16 + (l & 15);
        float bi = bias[col];
#pragma unroll
        for (int fm = 0; fm < 4; ++fm) {
            int s0 = (row0 & 1023) + wr * 64 + fm * 16 + (l >> 4) * 4;
            ushort4 hv;
            hv.x = bf16_hi(acc[fm][0] + bi);
            hv.y = bf16_hi(acc[fm][1] + bi);
            hv.z = bf16_hi(acc[fm][2] + bi);
            hv.w = bf16_hi(acc[fm][3] + bi);
            size_t off = ((size_t)(b * 256 + col)) * 1024 + s0;
            *(ushort4*)&h1t_h[off] = hv;
        }
    }
}

// ---------------------------------------------------------------------------
// fp32 VALU gemm_nt (proj only) + mv + plain-bf16 x emit
// ---------------------------------------------------------------------------
#define BM 64
#define BN 64
#define BK 16
__global__ __launch_bounds__(256) void gemm_nt_kernel(
    const float* __restrict__ A, const float* __restrict__ B,
    float* __restrict__ C, int K, float alpha, const float* __restrict__ bias,
    const float* __restrict__ abar, float* __restrict__ mv,
    unsigned short* __restrict__ xh)
{
    __shared__ float As[BK][BM + 4];
    __shared__ float Bs[BK][BN + 4];
    __shared__ float red[16][BN];
    const int tid = threadIdx.x;
    const int bm = blockIdx.x, bn = blockIdx.y;
    const int tx = tid & 15, ty = tid >> 4;
    const int lrow = tid >> 2;
    const int lk = (tid & 3) << 2;
    const float* Ag = A + (size_t)(bm * BM + lrow) * K + lk;
    const float* Bg = B + (size_t)(bn * BN + lrow) * K + lk;
    float acc[4][4] = {};

    for (int k0 = 0; k0 < K; k0 += BK) {
        float4 av = *(const float4*)(Ag + k0);
        float4 bv = *(const float4*)(Bg + k0);
        __syncthreads();
        As[lk + 0][lrow] = av.x; As[lk + 1][lrow] = av.y;
        As[lk + 2][lrow] = av.z; As[lk + 3][lrow] = av.w;
        Bs[lk + 0][lrow] = bv.x; Bs[lk + 1][lrow] = bv.y;
        Bs[lk + 2][lrow] = bv.z; Bs[lk + 3][lrow] = bv.w;
        __syncthreads();
#pragma unroll
        for (int kk = 0; kk < BK; ++kk) {
            const float4 a = *(const float4*)&As[kk][ty << 2];
            const float4 b = *(const float4*)&Bs[kk][tx << 2];
            float ar[4] = {a.x, a.y, a.z, a.w};
            float br[4] = {b.x, b.y, b.z, b.w};
#pragma unroll
            for (int i = 0; i < 4; ++i)
#pragma unroll
                for (int jj = 0; jj < 4; ++jj)
                    acc[i][jj] += ar[i] * br[jj];
        }
    }
    const int row = bm * BM + (ty << 2);
    const int col = bn * BN + (tx << 2);
    const int b = row >> 10;
    float bi[4] = {bias[col], bias[col + 1], bias[col + 2], bias[col + 3]};
    float o[4][4];
#pragma unroll
    for (int i = 0; i < 4; ++i) {
        float4 ov;
        ov.x = o[i][0] = alpha * acc[i][0] + bi[0];
        ov.y = o[i][1] = alpha * acc[i][1] + bi[1];
        ov.z = o[i][2] = alpha * acc[i][2] + bi[2];
        ov.w = o[i][3] = alpha * acc[i][3] + bi[3];
        *(float4*)(C + (size_t)(row + i) * CDIM + col) = ov;
        ushort4 hv;
        hv.x = bf16_hi(o[i][0]);
        hv.y = bf16_hi(o[i][1]);
        hv.z = bf16_hi(o[i][2]);
        hv.w = bf16_hi(o[i][3]);
        *(ushort4*)&xh[(size_t)(row + i) * CDIM + col] = hv;
    }
    {
        float p[4];
#pragma unroll
        for (int jj = 0; jj < 4; ++jj) {
            p[jj] = 0.f;
#pragma unroll
            for (int i = 0; i < 4; ++i)
                p[jj] += abar[((row + i) & 1023) + (b << 10)] * o[i][jj];
            red[ty][(tx << 2) + jj] = p[jj];
        }
        __syncthreads();
        if (tid < BN) {
            float s = 0.f;
#pragma unroll
            for (int tt = 0; tt < 16; ++tt) s += red[tt][tid];
            atomicAdd(&mv[b * CDIM + bn * BN + tid], s);
        }
    }
}

// ---------------------------------------------------------------------------
// color: writes tanh'd color table
// ---------------------------------------------------------------------------
__global__ __launch_bounds__(256) void color_kernel(
    const float* __restrict__ x, const float* __restrict__ rgb_w,
    const float* __restrict__ rgb_b, float* __restrict__ color, float sc_c)
{
    const int wave = threadIdx.x >> 6;
    const int lane = threadIdx.x & 63;
    const int r = blockIdx.x * 4 + wave;
    const float4 xv = *(const float4*)(x + (size_t)r * CDIM + lane * 4);
    float p[3];
#pragma unroll
    for (int cc = 0; cc < 3; ++cc) {
        const float4 wv = *(const float4*)(rgb_w + cc * CDIM + lane * 4);
        p[cc] = xv.x * wv.x + xv.y * wv.y + xv.z * wv.z + xv.w * wv.w;
    }
#pragma unroll
    for (int off = 32; off > 0; off >>= 1) {
#pragma unroll
        for (int cc = 0; cc < 3; ++cc) p[cc] += __shfl_down(p[cc], off);
    }
    if (lane == 0) {
#pragma unroll
        for (int cc = 0; cc < 3; ++cc)
            color[(size_t)r * 3 + cc] = tanhf(sc_c * p[cc] + rgb_b[cc]);
    }
}

// ---------------------------------------------------------------------------
// gather: 4 pixels/thread, float4 stores per plane
// ---------------------------------------------------------------------------
__global__ __launch_bounds__(256) void gather_kernel(
    const int* __restrict__ seg, const float* __restrict__ color,
    float* __restrict__ out)
{
    int idx = blockIdx.x * 256 + threadIdx.x;
    int b = idx >> 16;
    int p4 = idx & 65535;
    int4 s = ((const int4*)(seg + (size_t)b * N_PIX))[p4];
    const float* cb = color + (size_t)b * S_SEG * 3;
    float4 o0, o1, o2;
    o0.x = cb[s.x * 3 + 0]; o1.x = cb[s.x * 3 + 1]; o2.x = cb[s.x * 3 + 2];
    o0.y = cb[s.y * 3 + 0]; o1.y = cb[s.y * 3 + 1]; o2.y = cb[s.y * 3 + 2];
    o0.z = cb[s.z * 3 + 0]; o1.z = cb[s.z * 3 + 1]; o2.z = cb[s.z * 3 + 2];
    o0.w = cb[s.w * 3 + 0]; o1.w = cb[s.w * 3 + 1]; o2.w = cb[s.w * 3 + 2];
    ((float4*)(out + ((size_t)b * 3 + 0) * N_PIX))[p4] = o0;
    ((float4*)(out + ((size_t)b * 3 + 1) * N_PIX))[p4] = o1;
    ((float4*)(out + ((size_t)b * 3 + 2) * N_PIX))[p4] = o2;
}

// ---------------------------------------------------------------------------
extern "C" void kernel_launch(void* const* d_in, const int* in_sizes, int n_in,
                              void* d_out, int out_size, void* d_ws, size_t ws_size,
                              hipStream_t stream)
{
    (void)in_sizes; (void)n_in; (void)out_size; (void)ws_size;
    const float* z      = (const float*)d_in[0];
    const float* images = (const float*)d_in[1];
    const int*   seg    = (const int*)d_in[2];
    const float* A      = (const float*)d_in[3];
    const float* proj_w = (const float*)d_in[4];
    const float* proj_b = (const float*)d_in[5];
    const float* blk_w  = (const float*)d_in[6];
    const float* blk_b  = (const float*)d_in[7];
    const float* ada_w1 = (const float*)d_in[8];
    const float* ada_b1 = (const float*)d_in[9];
    const float* ada_w2 = (const float*)d_in[10];
    const float* ada_b2 = (const float*)d_in[11];
    const float* rgb_w  = (const float*)d_in[12];
    const float* rgb_b  = (const float*)d_in[13];
    float* out = (float*)d_out;

    float* ws = (float*)d_ws;
    float* mv       = ws;                   // 18432 (zeroed)
    float* sumabar  = ws + 18432;           // 16   (zeroed)
    float* abar     = ws + 18448;           // 8192
    float* style    = ws + 26640;           // 4096
    float* colr     = ws + 30736;           // 24576
    float* wpad     = ws + 55312;           // 36864
    float* xin      = ws + 92176;           // 1179648 -> 1271824
    float* x        = ws + 1271824;         // 2097152 -> 3368976
    unsigned short* xh    = (unsigned short*)(ws + 3368976);
    unsigned short* h1t_h = (unsigned short*)(ws + 5466128);
    unsigned short* Ah    = (unsigned short*)(ws + 7563280);   // 8M ushort
    unsigned short* Wh    = (unsigned short*)(ws + 15951888);
    unsigned short* Wl    = (unsigned short*)(ws + 16214032);
    float* seg_slab = ws + 16476176;        // 1048576 -> 17524752
    float* A_slab   = ws + 17524752;        // 262144  -> 17786896

    const float sc_in = (float)sqrt(2.0 / 131.0);
    const float sc_c  = (float)sqrt(2.0 / 256.0);
    const float sc_2c = (float)sqrt(2.0 / 512.0);

    (void)hipMemsetAsync(mv, 0, 18448 * sizeof(float), stream);
    prep_all_kernel<<<dim3(641), 1024, 0, stream>>>(
        images, seg, seg_slab, A, Ah, A_slab,
        blk_w, Wh, Wl, sc_c, proj_w, wpad);
    prep_xin_kernel<<<dim3(4640), 256, 0, stream>>>(
        seg_slab, A_slab, z, xin, abar, sumabar);

    gemm_nt_kernel<<<dim3(128, 4), 256, 0, stream>>>(xin, wpad, x, 144, sc_in, proj_b,
                                                     abar, mv, xh);

    for (int i = 0; i < 8; ++i) {
        gemm_nt_mfma_kernel<<<dim3(64, 5), 512, 0, stream>>>(
            xh, Wh + (size_t)i * 65536, Wl + (size_t)i * 65536,
            blk_b + i * CDIM, h1t_h,
            mv + i * 2048, sumabar, blk_w + (size_t)i * CDIM * CDIM,
            ada_w1 + (size_t)i * 512 * 256, ada_b1 + i * 512,
            ada_w2 + (size_t)i * 512 * 512, ada_b2 + i * 512,
            style, sc_c, sc_2c);
        const bool last = (i == 7);
        gemm_nn_mfma_kernel<<<dim3(256), 512, 0, stream>>>(
            Ah, h1t_h, style, abar,
            last ? x : nullptr,
            last ? nullptr : xh,
            last ? nullptr : (mv + (i + 1) * 2048));
    }

    color_kernel<<<dim3(2048), 256, 0, stream>>>(x, rgb_w, rgb_b, colr, sc_c);
    gather_kernel<<<dim3(2048), 256, 0, stream>>>(seg, colr, out);
}

// Round 18
// 442.238 us; speedup vs baseline: 1.2530x; 1.0026x over previous
//
#include <hip/hip_runtime.h>
#include <math.h>

#define N_PIX (512*512)
#define S_SEG 1024
#define CDIM  256
#define BATCH 8

typedef __attribute__((ext_vector_type(4))) float f32x4;
typedef __attribute__((ext_vector_type(8))) short bf16x8;
typedef __fp16 half2v __attribute__((ext_vector_type(2)));
typedef __attribute__((address_space(3))) unsigned int lds_uint;

__device__ __forceinline__ float lrelu(float v) { return v > 0.f ? v : 0.2f * v; }

__device__ __forceinline__ unsigned short bf16_hi(float x) {
    union { float f; unsigned int u; } v; v.f = x;
    unsigned int r = v.u + 0x7FFFu + ((v.u >> 16) & 1u);
    return (unsigned short)(r >> 16);
}
__device__ __forceinline__ float bf16_tof(unsigned short h) {
    union { float f; unsigned int u; } v; v.u = ((unsigned int)h) << 16;
    return v.f;
}
__device__ __forceinline__ float dot4(float4 a, float4 b) {
    return a.x * b.x + a.y * b.y + a.z * b.z + a.w * b.w;
}
__device__ __forceinline__ unsigned pack_h2(float lo, float hi) {
    union { half2v h; unsigned u; } c;
    c.h = __builtin_amdgcn_cvt_pkrtz(lo, hi);
    return c.u;
}
__device__ __forceinline__ void ds_pk_add(lds_uint* p, unsigned val) {
    asm volatile("ds_pk_add_f16 %0, %1"
                 :: "v"((unsigned)(unsigned long)p), "v"(val) : "memory");
}

// ---------------------------------------------------------------------------
// MERGED prep (R16 state: A -> Ah bf16 only, atomic-free flush)
// ---------------------------------------------------------------------------
__global__ __launch_bounds__(1024) void prep_all_kernel(
    const float* __restrict__ images, const int* __restrict__ seg,
    float* __restrict__ seg_slab,
    const float* __restrict__ A, unsigned short* __restrict__ Ah,
    float* __restrict__ A_slab,
    const float* __restrict__ blk_w, unsigned short* __restrict__ Wh,
    unsigned short* __restrict__ Wl, float sc_c,
    const float* __restrict__ proj_w, float* __restrict__ wpad)
{
    __shared__ unsigned int sm[4096];
    const int blk = blockIdx.x;
    const int t = threadIdx.x;

    if (blk < 256) {
        const int b = blk >> 5;
        const int chunk = blk & 31;
        for (int i = t; i < S_SEG * 2; i += 1024) sm[i] = 0u;
        __syncthreads();

        lds_uint* bl2 = (lds_uint*)sm;
        const float4* imr = (const float4*)(images + (size_t)b * 3 * N_PIX);
        const float4* img = imr + N_PIX / 4;
        const float4* imb = img + N_PIX / 4;
        const int4* sg4 = (const int4*)(seg + (size_t)b * N_PIX);
        const int base4 = chunk * (N_PIX / 32 / 4);

#pragma unroll
        for (int it = 0; it < 2; ++it) {
            int p4 = base4 + it * 1024 + t;
            int4 s = sg4[p4];
            float4 r = imr[p4];
            float4 g = img[p4];
            float4 bb = imb[p4];
            ds_pk_add(bl2 + s.x * 2 + 0, pack_h2(r.x, g.x));
            ds_pk_add(bl2 + s.x * 2 + 1, pack_h2(bb.x, 1.f));
            ds_pk_add(bl2 + s.y * 2 + 0, pack_h2(r.y, g.y));
            ds_pk_add(bl2 + s.y * 2 + 1, pack_h2(bb.y, 1.f));
            ds_pk_add(bl2 + s.z * 2 + 0, pack_h2(r.z, g.z));
            ds_pk_add(bl2 + s.z * 2 + 1, pack_h2(bb.z, 1.f));
            ds_pk_add(bl2 + s.w * 2 + 0, pack_h2(r.w, g.w));
            ds_pk_add(bl2 + s.w * 2 + 1, pack_h2(bb.w, 1.f));
        }
        __syncthreads();
        if (t < S_SEG) {
            union { unsigned u; __fp16 h[2]; } p0, p1;
            p0.u = sm[t * 2 + 0];
            p1.u = sm[t * 2 + 1];
            float4 o;
            o.x = (float)p0.h[0];
            o.y = (float)p0.h[1];
            o.z = (float)p1.h[0];
            o.w = (float)p1.h[1];
            ((float4*)seg_slab)[(size_t)blk * 1024 + t] = o;
        }
        return;
    }

    if (blk < 512) {
        const int ablk = blk - 256;
        const int b = ablk >> 5;
        const int chunk = ablk & 31;
        const int col = t & 255;
        const int rg = t >> 8;
        const size_t base4 = (((size_t)b * 1024 * 1024 + (size_t)chunk * 32 * 1024) >> 2)
                             + (size_t)rg * 8 * 256;
        const float4* Af = ((const float4*)A) + base4;
        ushort4* Ahf = ((ushort4*)Ah) + base4;
        float a0 = 0.f, a1 = 0.f, a2 = 0.f, a3 = 0.f;
#pragma unroll
        for (int r = 0; r < 8; ++r) {
            float4 v = Af[r * 256 + col];
            ushort4 h;
            h.x = bf16_hi(v.x);
            h.y = bf16_hi(v.y);
            h.z = bf16_hi(v.z);
            h.w = bf16_hi(v.w);
            Ahf[r * 256 + col] = h;
            a0 += v.x; a1 += v.y; a2 += v.z; a3 += v.w;
        }
        float4* red4 = (float4*)sm;
        float4 p; p.x = a0; p.y = a1; p.z = a2; p.w = a3;
        red4[rg * 256 + col] = p;
        __syncthreads();
        if (t < 256) {
            float4 s0 = red4[t], s1 = red4[256 + t], s2 = red4[512 + t], s3 = red4[768 + t];
            float4 o;
            o.x = s0.x + s1.x + s2.x + s3.x;
            o.y = s0.y + s1.y + s2.y + s3.y;
            o.z = s0.z + s1.z + s2.z + s3.z;
            o.w = s0.w + s1.w + s2.w + s3.w;
            ((float4*)A_slab)[(size_t)ablk * 256 + t] = o;
        }
        return;
    }

    if (blk < 640) {
        unsigned int idx = (blk - 512) * 1024 + t;
        float4 v = ((const float4*)blk_w)[idx];
        ushort4 h, l;
        float a;
        a = v.x * sc_c; h.x = bf16_hi(a); l.x = bf16_hi(a - bf16_tof(h.x));
        a = v.y * sc_c; h.y = bf16_hi(a); l.y = bf16_hi(a - bf16_tof(h.y));
        a = v.z * sc_c; h.z = bf16_hi(a); l.z = bf16_hi(a - bf16_tof(h.z));
        a = v.w * sc_c; h.w = bf16_hi(a); l.w = bf16_hi(a - bf16_tof(h.w));
        ((ushort4*)Wh)[idx] = h;
        ((ushort4*)Wl)[idx] = l;
        return;
    }

    for (int i = t; i < 256 * 144; i += 1024) {
        int n = i / 144, k = i % 144;
        wpad[i] = (k < 131) ? proj_w[n * 131 + k] : 0.f;
    }
}

// ---------------------------------------------------------------------------
// prep_xin + slab reductions (unchanged)
// ---------------------------------------------------------------------------
__global__ __launch_bounds__(256) void prep_xin_kernel(
    const float* __restrict__ seg_slab, const float* __restrict__ A_slab,
    const float* __restrict__ z, float* __restrict__ xin,
    float* __restrict__ abar, float* __restrict__ sumabar)
{
    const int t = threadIdx.x;
    if (blockIdx.x >= 4608) {
        int idx = (blockIdx.x - 4608) * 256 + t;
        int b = idx >> 10, s = idx & 1023;
        float acc = 0.f;
        const float* sl = A_slab + (size_t)(b << 5) * 1024 + s;
#pragma unroll 8
        for (int ch = 0; ch < 32; ++ch) acc += sl[ch * 1024];
        float v = acc * (1.f / 1024.f);
        abar[idx] = v;
        __shared__ float red[256];
        red[t] = v;
        __syncthreads();
        for (int off = 128; off > 0; off >>= 1) {
            if (t < off) red[t] += red[t + off];
            __syncthreads();
        }
        if (t == 0) atomicAdd(&sumabar[b], red[0]);
        return;
    }

    int idx = blockIdx.x * 256 + t;
    int r = idx / 144, c = idx % 144;
    int b = r >> 10;
    float v;
    if (c < 3) {
        int s = r & 1023;
        const float4* sl = (const float4*)seg_slab + (size_t)(b << 5) * 1024 + s;
        float cnt = 0.f, sc = 0.f;
#pragma unroll 8
        for (int ch = 0; ch < 32; ++ch) {
            float4 w = sl[ch * 1024];
            cnt += w.w;
            sc += (c == 0) ? w.x : ((c == 1) ? w.y : w.z);
        }
        v = sc / (cnt + 1e-6f);
    } else if (c < 131) {
        v = z[b * 128 + (c - 3)];
    } else {
        v = 0.f;
    }
    xin[idx] = v;
}

// ---------------------------------------------------------------------------
// staging helpers
// ---------------------------------------------------------------------------
__device__ __forceinline__ void stage_tile(
    const unsigned short* __restrict__ g, int grow,
    unsigned short* lds, int tid, int nissue, int T)
{
    for (int i = 0; i < nissue; ++i) {
        int c = i * T + tid;
        int row = c >> 3, cin = c & 7;
        int cs = cin ^ (row & 7);
        const unsigned short* src = g + (size_t)row * grow + cs * 8;
        unsigned short* dst = lds + (size_t)(i * T + (tid & ~63)) * 8;
        __builtin_amdgcn_global_load_lds(
            (const __attribute__((address_space(1))) unsigned int*)src,
            (__attribute__((address_space(3))) unsigned int*)dst, 16, 0, 0);
    }
}

__device__ __forceinline__ int frag_idx(int row, int ks, int l)
{
    int chunk = (ks * 4 + (l >> 4)) ^ (row & 7);
    return row * 64 + chunk * 8;
}

// ---------------------------------------------------------------------------
// MFMA GEMM: x_out = lrelu(gamma*(A @ h1) + beta). All plain bf16.
// ---------------------------------------------------------------------------
__global__ __launch_bounds__(512) void gemm_nn_mfma_kernel(
    const unsigned short* __restrict__ Ah_g,
    const unsigned short* __restrict__ Hh_g,
    const float* __restrict__ style, const float* __restrict__ abar,
    float* __restrict__ x, unsigned short* __restrict__ xh,
    float* __restrict__ mv)
{
    __shared__ __align__(16) unsigned short Ah_s[64 * 64];
    __shared__ __align__(16) unsigned short Bh_s[128 * 64];
    __shared__ float mvred[128];
    const int tid = threadIdx.x;
    const int bid = blockIdx.x;
    const int xcd = bid & 7;
    const int j = bid >> 3;
    const int pairidx = (xcd << 1) | (j >> 4);
    const int bm = j & 15;
    const int bn = pairidx & 1;
    const int b = pairidx >> 1;
    const int l = tid & 63, wave = tid >> 6;
    const int wr = wave >> 2, wc = wave & 3;
    if (mv && tid < 128) mvred[tid] = 0.f;

    const unsigned short* Ag_h = Ah_g + ((size_t)(b * 1024 + bm * 64)) * 1024;
    const unsigned short* Hg_h = Hh_g + ((size_t)(b * 256 + bn * 128)) * 1024;

    f32x4 acc[2][2];
#pragma unroll
    for (int i = 0; i < 2; ++i)
#pragma unroll
        for (int jj = 0; jj < 2; ++jj) acc[i][jj] = (f32x4){0.f, 0.f, 0.f, 0.f};

    for (int kt = 0; kt < 16; ++kt) {
        stage_tile(Ag_h + kt * 64, 1024, Ah_s, tid, 1, 512);
        stage_tile(Hg_h + kt * 64, 1024, Bh_s, tid, 2, 512);
        __syncthreads();
#pragma unroll
        for (int ks = 0; ks < 2; ++ks) {
            bf16x8 ah[2], bh[2];
#pragma unroll
            for (int fm = 0; fm < 2; ++fm) {
                int row = wr * 32 + fm * 16 + (l & 15);
                int idx = frag_idx(row, ks, l);
                ah[fm] = *(const bf16x8*)&Ah_s[idx];
            }
#pragma unroll
            for (int fn = 0; fn < 2; ++fn) {
                int row = wc * 32 + fn * 16 + (l & 15);
                int idx = frag_idx(row, ks, l);
                bh[fn] = *(const bf16x8*)&Bh_s[idx];
            }
#pragma unroll
            for (int fm = 0; fm < 2; ++fm)
#pragma unroll
                for (int fn = 0; fn < 2; ++fn)
                    acc[fm][fn] = __builtin_amdgcn_mfma_f32_16x16x32_bf16(ah[fm], bh[fn], acc[fm][fn], 0, 0, 0);
        }
        __syncthreads();
    }

    const float* st = style + b * 2 * CDIM;
#pragma unroll
    for (int fn = 0; fn < 2; ++fn) {
        int col = bn * 128 + wc * 32 + fn * 16 + (l & 15);
        float ga = st[col], be = st[CDIM + col];
        float pmv = 0.f;
#pragma unroll
        for (int fm = 0; fm < 2; ++fm) {
            int m0 = bm * 64 + wr * 32 + fm * 16 + (l >> 4) * 4;
#pragma unroll
            for (int r = 0; r < 4; ++r) {
                float v = lrelu(ga * acc[fm][fn][r] + be);
                size_t off = ((size_t)(b * 1024 + m0 + r)) * 256 + col;
                if (x) x[off] = v;
                if (xh) xh[off] = bf16_hi(v);
                pmv += abar[b * 1024 + m0 + r] * v;
            }
        }
        if (mv) atomicAdd(&mvred[wc * 32 + fn * 16 + (l & 15)], pmv);
    }
    if (mv) {
        __syncthreads();
        if (tid < 128) atomicAdd(&mv[b * 256 + bn * 128 + tid], mvred[tid]);
    }
}

// ---------------------------------------------------------------------------
// MFMA GEMM (h1 = x @ W'^T + b): x plain bf16, W split hi/lo. Output
// transposed plain bf16. PLUS style MLP (fp32 weights) at blockIdx.y == 4.
// ---------------------------------------------------------------------------
__global__ __launch_bounds__(512) void gemm_nt_mfma_kernel(
    const unsigned short* __restrict__ xh_g,
    const unsigned short* __restrict__ Wh, const unsigned short* __restrict__ Wl,
    const float* __restrict__ bias,
    unsigned short* __restrict__ h1t_h,
    const float* __restrict__ mv, const float* __restrict__ sumabar,
    const float* __restrict__ Wblk_f,
    const float* __restrict__ W1, const float* __restrict__ b1,
    const float* __restrict__ W2, const float* __restrict__ b2,
    float* __restrict__ style, float sc_c, float sc_2c)
{
    __shared__ __align__(16) unsigned short Ah_s[128 * 64];
    __shared__ __align__(16) unsigned short Bh_s[64 * 64];
    __shared__ __align__(16) unsigned short Bl_s[64 * 64];
    const int tid = threadIdx.x;
    const int bm = blockIdx.x, bn = blockIdx.y;

    if (bn == 4) {
        if (bm >= BATCH * 4) return;
        const int bb = bm >> 2;
        const int q = bm & 3;
        const int w = tid >> 6, lane = tid & 63;
        float* m_s = (float*)Ah_s;
        float* s1_s = (float*)Bh_s;

        const float4 mvreg = *(const float4*)&mv[bb * 256 + lane * 4];
        const float sab = sumabar[bb];

        for (int g = 0; g < 4; ++g) {
            const int o0 = w * 32 + g * 8;
            float p[8];
#pragma unroll
            for (int jj = 0; jj < 8; ++jj) {
                const float4 wv = *(const float4*)&Wblk_f[(size_t)(o0 + jj) * 256 + lane * 4];
                p[jj] = dot4(wv, mvreg);
            }
#pragma unroll
            for (int off = 32; off > 0; off >>= 1)
#pragma unroll
                for (int jj = 0; jj < 8; ++jj) p[jj] += __shfl_xor(p[jj], off);
            if (lane == 0)
#pragma unroll
                for (int jj = 0; jj < 8; ++jj)
                    m_s[o0 + jj] = sc_c * p[jj] + sab * bias[o0 + jj];
        }
        __syncthreads();
        const float4 mreg = *(const float4*)&m_s[lane * 4];

        for (int g = 0; g < 8; ++g) {
            const int o0 = w * 64 + g * 8;
            float p[8];
#pragma unroll
            for (int jj = 0; jj < 8; ++jj) {
                const float4 wv = *(const float4*)&W1[(size_t)(o0 + jj) * 256 + lane * 4];
                p[jj] = dot4(wv, mreg);
            }
#pragma unroll
            for (int off = 32; off > 0; off >>= 1)
#pragma unroll
                for (int jj = 0; jj < 8; ++jj) p[jj] += __shfl_xor(p[jj], off);
            if (lane == 0)
#pragma unroll
                for (int jj = 0; jj < 8; ++jj)
                    s1_s[o0 + jj] = lrelu(sc_c * p[jj] + b1[o0 + jj]);
        }
        __syncthreads();
        const float4 sa = *(const float4*)&s1_s[lane * 4];
        const float4 sb = *(const float4*)&s1_s[256 + lane * 4];

        for (int g = 0; g < 2; ++g) {
            const int o0 = q * 128 + w * 16 + g * 8;
            float p[8];
#pragma unroll
            for (int jj = 0; jj < 8; ++jj) {
                const float4 wa = *(const float4*)&W2[(size_t)(o0 + jj) * 512 + lane * 4];
                const float4 wb = *(const float4*)&W2[(size_t)(o0 + jj) * 512 + 256 + lane * 4];
                p[jj] = dot4(wa, sa) + dot4(wb, sb);
            }
#pragma unroll
            for (int off = 32; off > 0; off >>= 1)
#pragma unroll
                for (int jj = 0; jj < 8; ++jj) p[jj] += __shfl_xor(p[jj], off);
            if (lane == 0)
#pragma unroll
                for (int jj = 0; jj < 8; ++jj)
                    style[bb * 512 + o0 + jj] = sc_2c * p[jj] + b2[o0 + jj];
        }
        return;
    }

    // ---- GEMM path (8 waves, wave-tile 64x16) ----
    const int l = tid & 63, wave = tid >> 6;
    const int wr = wave >> 2, wc = wave & 3;
    const int row0 = bm * 128;
    const int b = row0 >> 10;

    const unsigned short* Ag_h = xh_g + (size_t)row0 * 256;
    const unsigned short* Bg_h = Wh + (size_t)(bn * 64) * 256;
    const unsigned short* Bg_l = Wl + (size_t)(bn * 64) * 256;

    f32x4 acc[4];
#pragma unroll
    for (int i = 0; i < 4; ++i) acc[i] = (f32x4){0.f, 0.f, 0.f, 0.f};

    for (int kt = 0; kt < 4; ++kt) {
        stage_tile(Ag_h + kt * 64, 256, Ah_s, tid, 2, 512);
        stage_tile(Bg_h + kt * 64, 256, Bh_s, tid, 1, 512);
        stage_tile(Bg_l + kt * 64, 256, Bl_s, tid, 1, 512);
        __syncthreads();
#pragma unroll
        for (int ks = 0; ks < 2; ++ks) {
            bf16x8 ah[4], bh, bl;
#pragma unroll
            for (int fm = 0; fm < 4; ++fm) {
                int row = wr * 64 + fm * 16 + (l & 15);
                int idx = frag_idx(row, ks, l);
                ah[fm] = *(const bf16x8*)&Ah_s[idx];
            }
            {
                int row = wc * 16 + (l & 15);
                int idx = frag_idx(row, ks, l);
                bh = *(const bf16x8*)&Bh_s[idx];
                bl = *(const bf16x8*)&Bl_s[idx];
            }
#pragma unroll
            for (int fm = 0; fm < 4; ++fm) {
                acc[fm] = __builtin_amdgcn_mfma_f32_16x16x32_bf16(ah[fm], bh, acc[fm], 0, 0, 0);
                acc[fm] = __builtin_amdgcn_mfma_f32_16x16x32_bf16(ah[fm], bl, acc[fm], 0, 0, 0);
            }
        }
        __syncthreads();
    }

    {
        int col = bn * 64 + wc * 16 + (l & 15);
        float bi = bias[col];
#pragma unroll
        for (int fm = 0; fm < 4; ++fm) {
            int s0 = (row0 & 1023) + wr * 64 + fm * 16 + (l >> 4) * 4;
            ushort4 hv;
            hv.x = bf16_hi(acc[fm][0] + bi);
            hv.y = bf16_hi(acc[fm][1] + bi);
            hv.z = bf16_hi(acc[fm][2] + bi);
            hv.w = bf16_hi(acc[fm][3] + bi);
            size_t off = ((size_t)(b * 256 + col)) * 1024 + s0;
            *(ushort4*)&h1t_h[off] = hv;
        }
    }
}

// ---------------------------------------------------------------------------
// fp32 VALU gemm_nt (proj only) + mv + plain-bf16 x emit (no dead fp32 write)
// ---------------------------------------------------------------------------
#define BM 64
#define BN 64
#define BK 16
__global__ __launch_bounds__(256) void gemm_nt_kernel(
    const float* __restrict__ A, const float* __restrict__ B,
    int K, float alpha, const float* __restrict__ bias,
    const float* __restrict__ abar, float* __restrict__ mv,
    unsigned short* __restrict__ xh)
{
    __shared__ float As[BK][BM + 4];
    __shared__ float Bs[BK][BN + 4];
    __shared__ float red[16][BN];
    const int tid = threadIdx.x;
    const int bm = blockIdx.x, bn = blockIdx.y;
    const int tx = tid & 15, ty = tid >> 4;
    const int lrow = tid >> 2;
    const int lk = (tid & 3) << 2;
    const float* Ag = A + (size_t)(bm * BM + lrow) * K + lk;
    const float* Bg = B + (size_t)(bn * BN + lrow) * K + lk;
    float acc[4][4] = {};

    for (int k0 = 0; k0 < K; k0 += BK) {
        float4 av = *(const float4*)(Ag + k0);
        float4 bv = *(const float4*)(Bg + k0);
        __syncthreads();
        As[lk + 0][lrow] = av.x; As[lk + 1][lrow] = av.y;
        As[lk + 2][lrow] = av.z; As[lk + 3][lrow] = av.w;
        Bs[lk + 0][lrow] = bv.x; Bs[lk + 1][lrow] = bv.y;
        Bs[lk + 2][lrow] = bv.z; Bs[lk + 3][lrow] = bv.w;
        __syncthreads();
#pragma unroll
        for (int kk = 0; kk < BK; ++kk) {
            const float4 a = *(const float4*)&As[kk][ty << 2];
            const float4 b = *(const float4*)&Bs[kk][tx << 2];
            float ar[4] = {a.x, a.y, a.z, a.w};
            float br[4] = {b.x, b.y, b.z, b.w};
#pragma unroll
            for (int i = 0; i < 4; ++i)
#pragma unroll
                for (int jj = 0; jj < 4; ++jj)
                    acc[i][jj] += ar[i] * br[jj];
        }
    }
    const int row = bm * BM + (ty << 2);
    const int col = bn * BN + (tx << 2);
    const int b = row >> 10;
    float bi[4] = {bias[col], bias[col + 1], bias[col + 2], bias[col + 3]};
    float o[4][4];
#pragma unroll
    for (int i = 0; i < 4; ++i) {
        o[i][0] = alpha * acc[i][0] + bi[0];
        o[i][1] = alpha * acc[i][1] + bi[1];
        o[i][2] = alpha * acc[i][2] + bi[2];
        o[i][3] = alpha * acc[i][3] + bi[3];
        ushort4 hv;
        hv.x = bf16_hi(o[i][0]);
        hv.y = bf16_hi(o[i][1]);
        hv.z = bf16_hi(o[i][2]);
        hv.w = bf16_hi(o[i][3]);
        *(ushort4*)&xh[(size_t)(row + i) * CDIM + col] = hv;
    }
    {
        float p[4];
#pragma unroll
        for (int jj = 0; jj < 4; ++jj) {
            p[jj] = 0.f;
#pragma unroll
            for (int i = 0; i < 4; ++i)
                p[jj] += abar[((row + i) & 1023) + (b << 10)] * o[i][jj];
            red[ty][(tx << 2) + jj] = p[jj];
        }
        __syncthreads();
        if (tid < BN) {
            float s = 0.f;
#pragma unroll
            for (int tt = 0; tt < 16; ++tt) s += red[tt][tid];
            atomicAdd(&mv[b * CDIM + bn * BN + tid], s);
        }
    }
}

// ---------------------------------------------------------------------------
// color: writes tanh'd color table
// ---------------------------------------------------------------------------
__global__ __launch_bounds__(256) void color_kernel(
    const float* __restrict__ x, const float* __restrict__ rgb_w,
    const float* __restrict__ rgb_b, float* __restrict__ color, float sc_c)
{
    const int wave = threadIdx.x >> 6;
    const int lane = threadIdx.x & 63;
    const int r = blockIdx.x * 4 + wave;
    const float4 xv = *(const float4*)(x + (size_t)r * CDIM + lane * 4);
    float p[3];
#pragma unroll
    for (int cc = 0; cc < 3; ++cc) {
        const float4 wv = *(const float4*)(rgb_w + cc * CDIM + lane * 4);
        p[cc] = xv.x * wv.x + xv.y * wv.y + xv.z * wv.z + xv.w * wv.w;
    }
#pragma unroll
    for (int off = 32; off > 0; off >>= 1) {
#pragma unroll
        for (int cc = 0; cc < 3; ++cc) p[cc] += __shfl_down(p[cc], off);
    }
    if (lane == 0) {
#pragma unroll
        for (int cc = 0; cc < 3; ++cc)
            color[(size_t)r * 3 + cc] = tanhf(sc_c * p[cc] + rgb_b[cc]);
    }
}

// ---------------------------------------------------------------------------
// gather: 4 pixels/thread, float4 stores per plane
// ---------------------------------------------------------------------------
__global__ __launch_bounds__(256) void gather_kernel(
    const int* __restrict__ seg, const float* __restrict__ color,
    float* __restrict__ out)
{
    int idx = blockIdx.x * 256 + threadIdx.x;
    int b = idx >> 16;
    int p4 = idx & 65535;
    int4 s = ((const int4*)(seg + (size_t)b * N_PIX))[p4];
    const float* cb = color + (size_t)b * S_SEG * 3;
    float4 o0, o1, o2;
    o0.x = cb[s.x * 3 + 0]; o1.x = cb[s.x * 3 + 1]; o2.x = cb[s.x * 3 + 2];
    o0.y = cb[s.y * 3 + 0]; o1.y = cb[s.y * 3 + 1]; o2.y = cb[s.y * 3 + 2];
    o0.z = cb[s.z * 3 + 0]; o1.z = cb[s.z * 3 + 1]; o2.z = cb[s.z * 3 + 2];
    o0.w = cb[s.w * 3 + 0]; o1.w = cb[s.w * 3 + 1]; o2.w = cb[s.w * 3 + 2];
    ((float4*)(out + ((size_t)b * 3 + 0) * N_PIX))[p4] = o0;
    ((float4*)(out + ((size_t)b * 3 + 1) * N_PIX))[p4] = o1;
    ((float4*)(out + ((size_t)b * 3 + 2) * N_PIX))[p4] = o2;
}

// ---------------------------------------------------------------------------
extern "C" void kernel_launch(void* const* d_in, const int* in_sizes, int n_in,
                              void* d_out, int out_size, void* d_ws, size_t ws_size,
                              hipStream_t stream)
{
    (void)in_sizes; (void)n_in; (void)out_size; (void)ws_size;
    const float* z      = (const float*)d_in[0];
    const float* images = (const float*)d_in[1];
    const int*   seg    = (const int*)d_in[2];
    const float* A      = (const float*)d_in[3];
    const float* proj_w = (const float*)d_in[4];
    const float* proj_b = (const float*)d_in[5];
    const float* blk_w  = (const float*)d_in[6];
    const float* blk_b  = (const float*)d_in[7];
    const float* ada_w1 = (const float*)d_in[8];
    const float* ada_b1 = (const float*)d_in[9];
    const float* ada_w2 = (const float*)d_in[10];
    const float* ada_b2 = (const float*)d_in[11];
    const float* rgb_w  = (const float*)d_in[12];
    const float* rgb_b  = (const float*)d_in[13];
    float* out = (float*)d_out;

    float* ws = (float*)d_ws;
    float* mv       = ws;                   // 18432 (zeroed)
    float* sumabar  = ws + 18432;           // 16   (zeroed)
    float* abar     = ws + 18448;           // 8192
    float* style    = ws + 26640;           // 4096
    float* colr     = ws + 30736;           // 24576
    float* wpad     = ws + 55312;           // 36864
    float* xin      = ws + 92176;           // 1179648 -> 1271824
    float* x        = ws + 1271824;         // 2097152 -> 3368976
    unsigned short* xh    = (unsigned short*)(ws + 3368976);
    unsigned short* h1t_h = (unsigned short*)(ws + 5466128);
    unsigned short* Ah    = (unsigned short*)(ws + 7563280);   // 8M ushort
    unsigned short* Wh    = (unsigned short*)(ws + 15951888);
    unsigned short* Wl    = (unsigned short*)(ws + 16214032);
    float* seg_slab = ws + 16476176;        // 1048576 -> 17524752
    float* A_slab   = ws + 17524752;        // 262144  -> 17786896

    const float sc_in = (float)sqrt(2.0 / 131.0);
    const float sc_c  = (float)sqrt(2.0 / 256.0);
    const float sc_2c = (float)sqrt(2.0 / 512.0);

    (void)hipMemsetAsync(mv, 0, 18448 * sizeof(float), stream);
    prep_all_kernel<<<dim3(641), 1024, 0, stream>>>(
        images, seg, seg_slab, A, Ah, A_slab,
        blk_w, Wh, Wl, sc_c, proj_w, wpad);
    prep_xin_kernel<<<dim3(4640), 256, 0, stream>>>(
        seg_slab, A_slab, z, xin, abar, sumabar);

    gemm_nt_kernel<<<dim3(128, 4), 256, 0, stream>>>(xin, wpad, 144, sc_in, proj_b,
                                                     abar, mv, xh);

    for (int i = 0; i < 8; ++i) {
        gemm_nt_mfma_kernel<<<dim3(64, 5), 512, 0, stream>>>(
            xh, Wh + (size_t)i * 65536, Wl + (size_t)i * 65536,
            blk_b + i * CDIM, h1t_h,
            mv + i * 2048, sumabar, blk_w + (size_t)i * CDIM * CDIM,
            ada_w1 + (size_t)i * 512 * 256, ada_b1 + i * 512,
            ada_w2 + (size_t)i * 512 * 512, ada_b2 + i * 512,
            style, sc_c, sc_2c);
        const bool last = (i == 7);
        gemm_nn_mfma_kernel<<<dim3(256), 512, 0, stream>>>(
            Ah, h1t_h, style, abar,
            last ? x : nullptr,
            last ? nullptr : xh,
            last ? nullptr : (mv + (i + 1) * 2048));
    }

    color_kernel<<<dim3(2048), 256, 0, stream>>>(x, rgb_w, rgb_b, colr, sc_c);
    gather_kernel<<<dim3(2048), 256, 0, stream>>>(seg, colr, out);
}